// Round 6
// baseline (659.713 us; speedup 1.0000x reference)
//
#include <hip/hip_runtime.h>
#include <hip/hip_bf16.h>
#include <cstdint>
#include <cstddef>

#define ALPHA 0.2f
#define MLP_SLOPE 0.01f

typedef short bf16x8 __attribute__((ext_vector_type(8)));
typedef float f32x4 __attribute__((ext_vector_type(4)));
typedef unsigned short ushort_t;

// raw barrier: syncs LDS exchange WITHOUT draining vmcnt (global prefetches
// stay in flight across it).
#define ASM_BARRIER() __asm__ __volatile__("s_waitcnt lgkmcnt(0)\n\ts_barrier" ::: "memory")

__device__ __forceinline__ float lrelu(float x, float s) { return x > 0.f ? x : x * s; }
__device__ __forceinline__ ushort_t f2bf(float x) {
  __hip_bfloat16 h = __float2bfloat16(x);
  return *reinterpret_cast<ushort_t*>(&h);
}
__device__ __forceinline__ float bf2f(ushort_t u) {
  union { unsigned int i; float f; } v; v.i = ((unsigned int)u) << 16; return v.f;
}

// ---------------------------------------------------------------------------
// cast fp32 -> bf16, 4 elems/thread
// ---------------------------------------------------------------------------
__global__ __launch_bounds__(256) void tobf(
    const float* __restrict__ in, ushort_t* __restrict__ outp)
{
  int idx = blockIdx.x * 256 + threadIdx.x;
  float4 v = ((const float4*)in)[idx];
  ushort4 h;
  h.x = f2bf(v.x); h.y = f2bf(v.y); h.z = f2bf(v.z); h.w = f2bf(v.w);
  ((ushort4*)outp)[idx] = h;
}

// ---------------------------------------------------------------------------
// zero a float buffer (s1/s2 init for atomics)
// ---------------------------------------------------------------------------
__global__ __launch_bounds__(256) void zero_f(float* __restrict__ p)
{
  int idx = blockIdx.x * 256 + threadIdx.x;
  ((float4*)p)[idx] = make_float4(0.f, 0.f, 0.f, 0.f);
}

// ---------------------------------------------------------------------------
// Pack weights W[K,N] (batch via blockIdx.y) into MFMA B-fragment order:
// frag(nblk,kblk) at ((nblk*(K/32)+kblk)*64+lane)*8; lo==nullptr -> hi only.
// ---------------------------------------------------------------------------
__global__ __launch_bounds__(256) void pack_wt(
    const float* __restrict__ W, ushort_t* __restrict__ hi,
    ushort_t* __restrict__ lo, int K, int N)
{
  int gid = blockIdx.x * 256 + threadIdx.x;   // [0, N*K/8)
  int lane = gid & 63;
  int kbc = K >> 5;
  int kblk = (gid >> 6) % kbc;
  int nblk = (gid >> 6) / kbc;
  size_t b = (size_t)blockIdx.y * K * N;
  int col = nblk * 16 + (lane & 15);
  int krow = kblk * 32 + (lane >> 4) * 8;
  ushort_t h[8] __attribute__((aligned(16)));
  ushort_t l[8] __attribute__((aligned(16)));
#pragma unroll
  for (int e = 0; e < 8; ++e) {
    float v = W[b + (size_t)(krow + e) * N + col];
    h[e] = f2bf(v);
    l[e] = f2bf(v - bf2f(h[e]));
  }
  *(uint4*)&hi[b + (size_t)gid * 8] = *(uint4*)h;
  if (lo) *(uint4*)&lo[b + (size_t)gid * 8] = *(uint4*)l;
}

// ---------------------------------------------------------------------------
// Fused h-GEMM: h = x@Wg (single-pass bf16), epilogue writes Bpack (B-frag
// order) + atomic s1/s2 dots. h never materialized in fp32.  (R9, frozen)
// ---------------------------------------------------------------------------
__global__ __launch_bounds__(256, 2) void gemm_h(
    const ushort_t* __restrict__ xb, const ushort_t* __restrict__ Wgp,
    const float* __restrict__ a1, const float* __restrict__ a2,
    ushort_t* __restrict__ Bpack, float* __restrict__ s1,
    float* __restrict__ s2)
{
  __shared__ ushort_t Ab[2][128][40];
  const int t = threadIdx.x;
  const int head = blockIdx.z;
  const int m0 = blockIdx.y * 128;
  const int n0 = blockIdx.x * 64;
  const int wave = t >> 6;
  const int wm = (wave & 1) * 64, wn = (wave >> 1) * 32;
  const int l16 = t & 15, quad = (t >> 4) & 3, l63 = t & 63;
  const int sr = t >> 1, sp = (t & 1) * 16;
  const ushort_t* arow_g = xb + (size_t)(m0 + sr) * 512 + sp;
  const ushort_t* bp = Wgp + (size_t)head * 256 * 512;
  const int nb0 = (n0 + wn) >> 4;

  f32x4 acc[4][2];
#pragma unroll
  for (int i = 0; i < 4; ++i)
#pragma unroll
    for (int j = 0; j < 2; ++j) acc[i][j] = (f32x4){0.f, 0.f, 0.f, 0.f};

  uint4 r0, r1;
  r0 = *(const uint4*)(arow_g);
  r1 = *(const uint4*)(arow_g + 8);
  *(uint4*)&Ab[0][sr][sp] = r0;
  *(uint4*)&Ab[0][sr][sp + 8] = r1;
  __syncthreads();

  for (int kb = 0; kb < 16; ++kb) {
    const int cur = kb & 1, nxt = cur ^ 1;
    if (kb < 15) {
      const ushort_t* p = arow_g + (kb + 1) * 32;
      r0 = *(const uint4*)p;
      r1 = *(const uint4*)(p + 8);
    }
    bf16x8 Bf[2];
#pragma unroll
    for (int nt = 0; nt < 2; ++nt)
      Bf[nt] = *(const bf16x8*)&bp[(((size_t)(nb0 + nt) * 16 + kb) * 64 + l63) * 8];
    bf16x8 Af[4];
#pragma unroll
    for (int mt = 0; mt < 4; ++mt)
      Af[mt] = *(const bf16x8*)&Ab[cur][wm + mt * 16 + l16][quad * 8];
#pragma unroll
    for (int mt = 0; mt < 4; ++mt)
#pragma unroll
      for (int nt = 0; nt < 2; ++nt)
        acc[mt][nt] = __builtin_amdgcn_mfma_f32_16x16x32_bf16(
            Af[mt], Bf[nt], acc[mt][nt], 0, 0, 0);
    if (kb < 15) {
      *(uint4*)&Ab[nxt][sr][sp] = r0;
      *(uint4*)&Ab[nxt][sr][sp + 8] = r1;
    }
    __syncthreads();
  }

  // ---- epilogue 1: write Bpack in B-fragment order (bf16) ----
#pragma unroll
  for (int mt = 0; mt < 4; ++mt)
#pragma unroll
    for (int nt = 0; nt < 2; ++nt)
#pragma unroll
      for (int rg = 0; rg < 4; ++rg) {
        int j = m0 + wm + mt * 16 + quad * 4 + rg;
        int c = n0 + wn + nt * 16 + l16;
        int kblk = j >> 5;
        int laneb = ((j >> 3) & 3) * 16 + (c & 15);
        int e = j & 7;
        Bpack[(((size_t)head * 256 + kblk) * 16 + (c >> 4)) * 512 + laneb * 8 + e] =
            f2bf(acc[mt][nt][rg]);
      }
  // ---- epilogue 2: s1/s2 partial dots, shuffle-reduced over 16 cols ----
  float a1v[2], a2v[2];
#pragma unroll
  for (int nt = 0; nt < 2; ++nt) {
    int c = n0 + wn + nt * 16 + l16;
    a1v[nt] = a1[head * 256 + c];
    a2v[nt] = a2[head * 256 + c];
  }
#pragma unroll
  for (int mt = 0; mt < 4; ++mt)
#pragma unroll
    for (int rg = 0; rg < 4; ++rg) {
      float p1 = acc[mt][0][rg] * a1v[0] + acc[mt][1][rg] * a1v[1];
      float p2 = acc[mt][0][rg] * a2v[0] + acc[mt][1][rg] * a2v[1];
      p1 += __shfl_xor(p1, 1); p2 += __shfl_xor(p2, 1);
      p1 += __shfl_xor(p1, 2); p2 += __shfl_xor(p2, 2);
      p1 += __shfl_xor(p1, 4); p2 += __shfl_xor(p2, 4);
      p1 += __shfl_xor(p1, 8); p2 += __shfl_xor(p2, 8);
      if (l16 == 0) {
        int row = m0 + wm + mt * 16 + quad * 4 + rg;
        atomicAdd(&s1[head * 8192 + row], p1);
        atomicAdd(&s2[head * 8192 + row], p2);
      }
    }
}

// ---------------------------------------------------------------------------
// Pipelined split-bf16 MLP GEMM (R9, frozen).
// ---------------------------------------------------------------------------
__global__ __launch_bounds__(256, 2) void gemm_mlp(
    const ushort_t* __restrict__ Ahi, const ushort_t* __restrict__ Alo,
    const ushort_t* __restrict__ Bph, const ushort_t* __restrict__ Bpl,
    const float* __restrict__ bias, float* __restrict__ Cf,
    ushort_t* __restrict__ Chi, ushort_t* __restrict__ Clo,
    int M, int N, int K, float slope)
{
  __shared__ ushort_t Ah[2][128][40], Al[2][128][40];
  const int kbc = K >> 5;
  const int t = threadIdx.x;
  const int m0 = blockIdx.y * 128;
  const int n0 = blockIdx.x * 64;
  const int wave = t >> 6;
  const int wm = (wave & 1) * 64, wn = (wave >> 1) * 32;
  const int l16 = t & 15, quad = (t >> 4) & 3, l63 = t & 63;
  const int sr = t >> 1, sp = (t & 1) * 16;
  const ushort_t* ah_g = Ahi + (size_t)(m0 + sr) * K + sp;
  const ushort_t* al_g = Alo + (size_t)(m0 + sr) * K + sp;
  const int nb0 = (n0 + wn) >> 4;

  f32x4 acc[4][2];
#pragma unroll
  for (int i = 0; i < 4; ++i)
#pragma unroll
    for (int j = 0; j < 2; ++j) acc[i][j] = (f32x4){0.f, 0.f, 0.f, 0.f};

  uint4 rh0, rh1, rl0, rl1;
  rh0 = *(const uint4*)(ah_g);
  rh1 = *(const uint4*)(ah_g + 8);
  rl0 = *(const uint4*)(al_g);
  rl1 = *(const uint4*)(al_g + 8);
  *(uint4*)&Ah[0][sr][sp] = rh0;
  *(uint4*)&Ah[0][sr][sp + 8] = rh1;
  *(uint4*)&Al[0][sr][sp] = rl0;
  *(uint4*)&Al[0][sr][sp + 8] = rl1;
  __syncthreads();

  for (int kb = 0; kb < kbc; ++kb) {
    const int cur = kb & 1, nxt = cur ^ 1;
    if (kb + 1 < kbc) {
      const ushort_t* ph = ah_g + (kb + 1) * 32;
      const ushort_t* plo = al_g + (kb + 1) * 32;
      rh0 = *(const uint4*)ph;
      rh1 = *(const uint4*)(ph + 8);
      rl0 = *(const uint4*)plo;
      rl1 = *(const uint4*)(plo + 8);
    }
    bf16x8 bh[2], bl[2];
#pragma unroll
    for (int nt = 0; nt < 2; ++nt) {
      size_t o = (((size_t)(nb0 + nt) * kbc + kb) * 64 + l63) * 8;
      bh[nt] = *(const bf16x8*)&Bph[o];
      bl[nt] = *(const bf16x8*)&Bpl[o];
    }
    bf16x8 afh[4], afl[4];
#pragma unroll
    for (int mt = 0; mt < 4; ++mt) {
      afh[mt] = *(const bf16x8*)&Ah[cur][wm + mt * 16 + l16][quad * 8];
      afl[mt] = *(const bf16x8*)&Al[cur][wm + mt * 16 + l16][quad * 8];
    }
#pragma unroll
    for (int mt = 0; mt < 4; ++mt)
#pragma unroll
      for (int nt = 0; nt < 2; ++nt) {
        acc[mt][nt] = __builtin_amdgcn_mfma_f32_16x16x32_bf16(afh[mt], bh[nt], acc[mt][nt], 0, 0, 0);
        acc[mt][nt] = __builtin_amdgcn_mfma_f32_16x16x32_bf16(afh[mt], bl[nt], acc[mt][nt], 0, 0, 0);
        acc[mt][nt] = __builtin_amdgcn_mfma_f32_16x16x32_bf16(afl[mt], bh[nt], acc[mt][nt], 0, 0, 0);
      }
    if (kb + 1 < kbc) {
      *(uint4*)&Ah[nxt][sr][sp] = rh0;
      *(uint4*)&Ah[nxt][sr][sp + 8] = rh1;
      *(uint4*)&Al[nxt][sr][sp] = rl0;
      *(uint4*)&Al[nxt][sr][sp + 8] = rl1;
    }
    __syncthreads();
  }

#pragma unroll
  for (int mt = 0; mt < 4; ++mt)
#pragma unroll
    for (int nt = 0; nt < 2; ++nt)
#pragma unroll
      for (int rg = 0; rg < 4; ++rg) {
        int m = m0 + wm + mt * 16 + quad * 4 + rg;
        int n = n0 + wn + nt * 16 + l16;
        float v = lrelu(acc[mt][nt][rg] + bias[n], slope);
        size_t o = (size_t)m * N + n;
        if (Cf) Cf[o] = v;
        if (Chi) {
          ushort_t h = f2bf(v);
          Chi[o] = h; Clo[o] = f2bf(v - bf2f(h));
        }
      }
}

// ---------------------------------------------------------------------------
// MFMA attention v13: SELF-GENERATING WAVES -- zero barriers, zero LDS.
// R1-R5 eliminated: Bf latency (R3 neutral), barrier count (R4 worse),
// occupancy (R5 worse). Remaining suspect: the cross-wave gen->LDS->consume
// exchange phase-locking all 8 waves every kt. Here each wave is fully
// independent: 8 waves = (2 head x 4 rowgroups of 32). Each lane generates
// exactly the A-fragments it consumes (A-frag layout: lane holds row=l&15,
// k=(l>>4)*8+e): 2 frags x 8 exps = 16 exps/lane/kt -- SAME total exp work
// as v8 (rg8 partitions rows, head partitions heads; no duplication).
// adj wave footprint unchanged (16 rows x 128B lines). Numerator MFMA
// order bitwise-identical to v8; denominator reduce tree isomorphic
// (4 octet partials, pairwise shfl) -> absmax should match exactly.
// No asm clobbers -> compiler free to software-pipeline globally.
// Regs: acc 128 + Bq 16 + 2 fetch sets ~48 + misc ~30 = ~220 < 252. 1 blk/CU.
// ---------------------------------------------------------------------------
__global__ __launch_bounds__(512, 1) void attn_mfma8(
    const ushort_t* __restrict__ Bpack, const float* __restrict__ s1g,
    const float* __restrict__ s2g, const int* __restrict__ adj,
    ushort_t* __restrict__ pacc, float* __restrict__ pl)
{
  const int t = threadIdx.x;
  const int i0 = blockIdx.x * 128;
  const int js = blockIdx.y;
  const int kbase = js * 2048;
  const int wave = t >> 6;
  const int head = wave >> 2;            // 0..1
  const int rg8 = wave & 3;              // 0..3 -> 32-row group
  const int l63 = t & 63;
  const int l15 = t & 15;
  const int oct = l63 >> 4;              // k-octet 0..3
  const int row0 = i0 + rg8 * 32 + l15;  // mt=0 row of this lane
  const float s1v0 = s1g[head * 8192 + row0];
  const float s1v1 = s1g[head * 8192 + row0 + 16];
  const float* s2h = s2g + head * 8192;
  const int* arow0 = adj + (size_t)row0 * 8192;
  const int* arow1 = arow0 + (size_t)16 * 8192;

  f32x4 acc[2][16];
#pragma unroll
  for (int m = 0; m < 2; ++m)
#pragma unroll
    for (int n = 0; n < 16; ++n) acc[m][n] = (f32x4){0.f, 0.f, 0.f, 0.f};
  float rs0 = 0.f, rs1 = 0.f;

  // two named prefetch sets (static indexing only)
  int4 A0a, A0b, A1a, A1b, B0a, B0b, B1a, B1b;
  float4 Asa, Asb, Bsa, Bsb;

  auto fetchA = [&](int kt) {
    int c = kbase + kt * 32 + oct * 8;
    A0a = *(const int4*)&arow0[c]; A0b = *(const int4*)&arow0[c + 4];
    A1a = *(const int4*)&arow1[c]; A1b = *(const int4*)&arow1[c + 4];
    Asa = *(const float4*)&s2h[c]; Asb = *(const float4*)&s2h[c + 4];
  };
  auto fetchB = [&](int kt) {
    int c = kbase + kt * 32 + oct * 8;
    B0a = *(const int4*)&arow0[c]; B0b = *(const int4*)&arow0[c + 4];
    B1a = *(const int4*)&arow1[c]; B1b = *(const int4*)&arow1[c + 4];
    Bsa = *(const float4*)&s2h[c]; Bsb = *(const float4*)&s2h[c + 4];
  };
  // gen one A-fragment: 8 exps for (row = this lane's row, k-octet = oct)
  auto genfrag = [&](int4 aa, int4 ab, float s1v, float4 sa, float4 sb,
                     float& rs) -> bf16x8 {
    int am[8] = {aa.x, aa.y, aa.z, aa.w, ab.x, ab.y, ab.z, ab.w};
    float sv[8] = {sa.x, sa.y, sa.z, sa.w, sb.x, sb.y, sb.z, sb.w};
    ushort_t w[8] __attribute__((aligned(16)));
#pragma unroll
    for (int e = 0; e < 8; ++e) {
      float e0 = s1v + sv[e];
      e0 = fmaxf(e0, 0.f) + ALPHA * fminf(e0, 0.f);
      float v = am[e] > 0 ? __expf(e0) : 0.f;
      rs += v;
      w[e] = f2bf(v);
    }
    return *(bf16x8*)w;
  };
  auto mstep = [&](bf16x8 af0, bf16x8 af1, int kt) {
    const ushort_t* bb =
        Bpack + (((size_t)head * 256 + (js * 64 + kt)) * 16 * 64 + l63) * 8;
    bf16x8 Bq[4];
#pragma unroll
    for (int q = 0; q < 4; ++q) Bq[q] = *(const bf16x8*)&bb[q * 512];
#pragma unroll
    for (int nt = 0; nt < 16; ++nt) {
      bf16x8 bcur = Bq[nt & 3];
      if (nt < 12) Bq[nt & 3] = *(const bf16x8*)&bb[(nt + 4) * 512];
      acc[0][nt] = __builtin_amdgcn_mfma_f32_16x16x32_bf16(
          af0, bcur, acc[0][nt], 0, 0, 0);
      acc[1][nt] = __builtin_amdgcn_mfma_f32_16x16x32_bf16(
          af1, bcur, acc[1][nt], 0, 0, 0);
    }
  };

  fetchA(0);
#pragma unroll 1
  for (int kt = 0; kt < 64; kt += 2) {
    fetchB(kt + 1);
    bf16x8 a0 = genfrag(A0a, A0b, s1v0, Asa, Asb, rs0);
    bf16x8 a1 = genfrag(A1a, A1b, s1v1, Asa, Asb, rs1);
    mstep(a0, a1, kt);
    if (kt + 2 < 64) fetchA(kt + 2);
    bf16x8 b0 = genfrag(B0a, B0b, s1v0, Bsa, Bsb, rs0);
    bf16x8 b1 = genfrag(B1a, B1b, s1v1, Bsa, Bsb, rs1);
    mstep(b0, b1, kt + 1);
  }

  // denominators: sum the 4 octet partials per row (pairwise tree as v8)
  rs0 += __shfl_xor(rs0, 16); rs0 += __shfl_xor(rs0, 32);
  rs1 += __shfl_xor(rs1, 16); rs1 += __shfl_xor(rs1, 32);
  if (oct == 0) {
    pl[((size_t)js * 2 + head) * 8192 + row0] = rs0;
    pl[((size_t)js * 2 + head) * 8192 + row0 + 16] = rs1;
  }
  // store bf16 partial numerators (C-frag: col=lane&15, row=(lane>>4)*4+rg)
#pragma unroll
  for (int mt = 0; mt < 2; ++mt)
#pragma unroll
    for (int nt = 0; nt < 16; ++nt)
#pragma unroll
      for (int rg = 0; rg < 4; ++rg) {
        int row = i0 + rg8 * 32 + mt * 16 + oct * 4 + rg;
        int col = nt * 16 + l15;
        pacc[(((size_t)js * 2 + head) * 8192 + row) * 256 + col] =
            f2bf(acc[mt][nt][rg]);
      }
}

// ---------------------------------------------------------------------------
// Finalize (R9, frozen): emits embed directly as hi/lo bf16 split.
// ---------------------------------------------------------------------------
__global__ __launch_bounds__(256) void attn_finalize(
    const ushort_t* __restrict__ pacc, const float* __restrict__ pl,
    const float* __restrict__ bg, const float* __restrict__ llm,
    ushort_t* __restrict__ ehi, ushort_t* __restrict__ elo)
{
  __shared__ float red[8];
  const int r = blockIdx.x;
  const int t = threadIdx.x;
  const int wv = t >> 6, lane = t & 63;
#pragma unroll
  for (int half = 0; half < 2; ++half) {
    float lv = llm[(size_t)r * 512 + half * 256 + t];
    ushort_t h = f2bf(lv);
    ehi[(size_t)r * 768 + half * 256 + t] = h;
    elo[(size_t)r * 768 + half * 256 + t] = f2bf(lv - bf2f(h));
  }
  float o[2];
#pragma unroll
  for (int hh = 0; hh < 2; ++hh) {
    float num = 0.f, l = 0.f;
#pragma unroll
    for (int js = 0; js < 4; ++js) {
      num += bf2f(pacc[(((size_t)js * 2 + hh) * 8192 + r) * 256 + t]);
      l += pl[((size_t)js * 2 + hh) * 8192 + r];
    }
    o[hh] = lrelu(num / l, ALPHA);
  }
  float v0 = o[0] * o[0], v1 = o[1] * o[1];
  for (int off = 32; off > 0; off >>= 1) {
    v0 += __shfl_xor(v0, off);
    v1 += __shfl_xor(v1, off);
  }
  if (lane == 0) { red[wv] = v0; red[4 + wv] = v1; }
  __syncthreads();
  float n0 = fmaxf(sqrtf(red[0] + red[1] + red[2] + red[3]), 1e-12f);
  float n1 = fmaxf(sqrtf(red[4] + red[5] + red[6] + red[7]), 1e-12f);
  float val = 0.5f * (o[0] / n0 + bg[t] + o[1] / n1 + bg[256 + t]);
  ushort_t h = f2bf(val);
  ehi[(size_t)r * 768 + 512 + t] = h;
  elo[(size_t)r * 768 + 512 + t] = f2bf(val - bf2f(h));
}

// ---------------------------------------------------------------------------
__global__ __launch_bounds__(256) void pred_kernel(
    const float* __restrict__ z2, const int* __restrict__ ts,
    float* __restrict__ out, int E)
{
  const int gw = (blockIdx.x * 256 + threadIdx.x) >> 6;
  const int lane = threadIdx.x & 63;
  if (gw >= E) return;
  const int a = ts[gw * 2], b = ts[gw * 2 + 1];
  float4 va = ((const float4*)(z2 + (size_t)a * 256))[lane];
  float4 vb = ((const float4*)(z2 + (size_t)b * 256))[lane];
  float p = va.x * vb.x + va.y * vb.y + va.z * vb.z + va.w * vb.w;
  for (int off = 32; off > 0; off >>= 1) p += __shfl_xor(p, off);
  if (lane == 0) out[gw] = p;
}

// ---------------------------------------------------------------------------
extern "C" void kernel_launch(void* const* d_in, const int* in_sizes, int n_in,
                              void* d_out, int out_size, void* d_ws, size_t ws_size,
                              hipStream_t stream) {
  const float* x   = (const float*)d_in[0];
  const int*   adj = (const int*)d_in[1];
  const int*   ts  = (const int*)d_in[2];
  const float* llm = (const float*)d_in[3];
  const float* Wg  = (const float*)d_in[4];
  const float* a1  = (const float*)d_in[5];
  const float* a2  = (const float*)d_in[6];
  const float* bg  = (const float*)d_in[7];
  const float* W1  = (const float*)d_in[8];
  const float* b1  = (const float*)d_in[9];
  const float* W2  = (const float*)d_in[10];
  const float* b2  = (const float*)d_in[11];
  float* out = (float*)d_out;
  float* ws  = (float*)d_ws;
  const int E = in_sizes[2] / 2;

  // ---- workspace layout (float words) ----
  ushort_t* xb    = (ushort_t*)(ws + 0);            //  8192x512 bf16
  ushort_t* Wgp   = (ushort_t*)(ws + 2097152);      //  2x512x256
  ushort_t* W1ph  = (ushort_t*)(ws + 2228224);      //  768x512
  ushort_t* W1pl  = (ushort_t*)(ws + 2424832);
  ushort_t* W2ph  = (ushort_t*)(ws + 2621440);      //  512x256
  ushort_t* W2pl  = (ushort_t*)(ws + 2686976);
  ushort_t* Bpack = (ushort_t*)(ws + 2752512);      //  2x8192x256
  float*    s1    = ws + 4849664;                   //  2x8192
  float*    s2    = ws + 4866048;
  float*    pl    = ws + 4882432;                   //  8x8192
  ushort_t* pacc  = (ushort_t*)(ws + 4947968);      //  8x8192x256
  ushort_t* ehi   = (ushort_t*)(ws + 13336576);     //  8192x768
  ushort_t* elo   = (ushort_t*)(ws + 16482304);
  ushort_t* z1hi  = (ushort_t*)(ws + 19628032);     //  8192x512
  ushort_t* z1lo  = (ushort_t*)(ws + 21725184);
  float*    z2    = ws + 23822336;                  //  8192x256 f32

  // 1. prep: casts, weight packing, s-zero
  tobf<<<4096, 256, 0, stream>>>(x, xb);
  pack_wt<<<dim3(64, 2), 256, 0, stream>>>(Wg, Wgp, nullptr, 512, 256);
  pack_wt<<<dim3(192, 1), 256, 0, stream>>>(W1, W1ph, W1pl, 768, 512);
  pack_wt<<<dim3(64, 1), 256, 0, stream>>>(W2, W2ph, W2pl, 512, 256);
  zero_f<<<32, 256, 0, stream>>>(s1);   // covers s1 and s2 (contiguous)
  // 2. fused h-GEMM -> Bpack + s1/s2 (hbuf never materialized)
  gemm_h<<<dim3(4, 64, 2), 256, 0, stream>>>(xb, Wgp, a1, a2, Bpack, s1, s2);
  // 3. MFMA attention partials (self-gen waves, no barriers, no LDS)
  attn_mfma8<<<dim3(64, 4), 512, 0, stream>>>(Bpack, s1, s2, adj, pacc, pl);
  // 4. finalize -> embed emitted directly as hi/lo split (llm inline)
  attn_finalize<<<8192, 256, 0, stream>>>(pacc, pl, bg, llm, ehi, elo);
  // 5. z1 = LR(embed @ W1 + b1) -> hi/lo
  gemm_mlp<<<dim3(8, 64), 256, 0, stream>>>(
      ehi, elo, W1ph, W1pl, b1, nullptr, z1hi, z1lo, 8192, 512, 768, MLP_SLOPE);
  // 6. z2 = LR(z1 @ W2 + b2) -> fp32
  gemm_mlp<<<dim3(4, 64), 256, 0, stream>>>(
      z1hi, z1lo, W2ph, W2pl, b2, z2, nullptr, nullptr, 8192, 256, 512, MLP_SLOPE);
  // 7. edge dots
  pred_kernel<<<(E * 64 + 255) / 256, 256, 0, stream>>>(z2, ts, out, E);
}

// Round 7
// 598.994 us; speedup vs baseline: 1.1014x; 1.1014x over previous
//
#include <hip/hip_runtime.h>
#include <hip/hip_bf16.h>
#include <cstdint>
#include <cstddef>

#define ALPHA 0.2f
#define MLP_SLOPE 0.01f

typedef short bf16x8 __attribute__((ext_vector_type(8)));
typedef float f32x4 __attribute__((ext_vector_type(4)));
typedef unsigned short ushort_t;

// raw barrier: syncs LDS exchange WITHOUT draining vmcnt (global prefetches
// stay in flight across it).
#define ASM_BARRIER() __asm__ __volatile__("s_waitcnt lgkmcnt(0)\n\ts_barrier" ::: "memory")

__device__ __forceinline__ float lrelu(float x, float s) { return x > 0.f ? x : x * s; }
__device__ __forceinline__ ushort_t f2bf(float x) {
  __hip_bfloat16 h = __float2bfloat16(x);
  return *reinterpret_cast<ushort_t*>(&h);
}
__device__ __forceinline__ float bf2f(ushort_t u) {
  union { unsigned int i; float f; } v; v.i = ((unsigned int)u) << 16; return v.f;
}

// ---------------------------------------------------------------------------
// cast fp32 -> bf16, 4 elems/thread
// ---------------------------------------------------------------------------
__global__ __launch_bounds__(256) void tobf(
    const float* __restrict__ in, ushort_t* __restrict__ outp)
{
  int idx = blockIdx.x * 256 + threadIdx.x;
  float4 v = ((const float4*)in)[idx];
  ushort4 h;
  h.x = f2bf(v.x); h.y = f2bf(v.y); h.z = f2bf(v.z); h.w = f2bf(v.w);
  ((ushort4*)outp)[idx] = h;
}

// ---------------------------------------------------------------------------
// zero a float buffer (s1/s2 init for atomics)
// ---------------------------------------------------------------------------
__global__ __launch_bounds__(256) void zero_f(float* __restrict__ p)
{
  int idx = blockIdx.x * 256 + threadIdx.x;
  ((float4*)p)[idx] = make_float4(0.f, 0.f, 0.f, 0.f);
}

// ---------------------------------------------------------------------------
// exp tables for separable attention weights: e2 = exp(s2), ea2 = exp(a*s2).
// Runs after gemm_h (s2 finalized). 2 heads x 8192 = 16384 values.
// ---------------------------------------------------------------------------
__global__ __launch_bounds__(256) void exp_tabs(
    const float* __restrict__ s2, float* __restrict__ e2,
    float* __restrict__ ea2)
{
  int i = blockIdx.x * 256 + threadIdx.x;
  float v = s2[i];
  e2[i] = __expf(v);
  ea2[i] = __expf(ALPHA * v);
}

// ---------------------------------------------------------------------------
// Pack weights W[K,N] (batch via blockIdx.y) into MFMA B-fragment order:
// frag(nblk,kblk) at ((nblk*(K/32)+kblk)*64+lane)*8; lo==nullptr -> hi only.
// ---------------------------------------------------------------------------
__global__ __launch_bounds__(256) void pack_wt(
    const float* __restrict__ W, ushort_t* __restrict__ hi,
    ushort_t* __restrict__ lo, int K, int N)
{
  int gid = blockIdx.x * 256 + threadIdx.x;   // [0, N*K/8)
  int lane = gid & 63;
  int kbc = K >> 5;
  int kblk = (gid >> 6) % kbc;
  int nblk = (gid >> 6) / kbc;
  size_t b = (size_t)blockIdx.y * K * N;
  int col = nblk * 16 + (lane & 15);
  int krow = kblk * 32 + (lane >> 4) * 8;
  ushort_t h[8] __attribute__((aligned(16)));
  ushort_t l[8] __attribute__((aligned(16)));
#pragma unroll
  for (int e = 0; e < 8; ++e) {
    float v = W[b + (size_t)(krow + e) * N + col];
    h[e] = f2bf(v);
    l[e] = f2bf(v - bf2f(h[e]));
  }
  *(uint4*)&hi[b + (size_t)gid * 8] = *(uint4*)h;
  if (lo) *(uint4*)&lo[b + (size_t)gid * 8] = *(uint4*)l;
}

// ---------------------------------------------------------------------------
// Fused h-GEMM: h = x@Wg (single-pass bf16), epilogue writes Bpack (B-frag
// order) + atomic s1/s2 dots. h never materialized in fp32.  (R9, frozen)
// ---------------------------------------------------------------------------
__global__ __launch_bounds__(256, 2) void gemm_h(
    const ushort_t* __restrict__ xb, const ushort_t* __restrict__ Wgp,
    const float* __restrict__ a1, const float* __restrict__ a2,
    ushort_t* __restrict__ Bpack, float* __restrict__ s1,
    float* __restrict__ s2)
{
  __shared__ ushort_t Ab[2][128][40];
  const int t = threadIdx.x;
  const int head = blockIdx.z;
  const int m0 = blockIdx.y * 128;
  const int n0 = blockIdx.x * 64;
  const int wave = t >> 6;
  const int wm = (wave & 1) * 64, wn = (wave >> 1) * 32;
  const int l16 = t & 15, quad = (t >> 4) & 3, l63 = t & 63;
  const int sr = t >> 1, sp = (t & 1) * 16;
  const ushort_t* arow_g = xb + (size_t)(m0 + sr) * 512 + sp;
  const ushort_t* bp = Wgp + (size_t)head * 256 * 512;
  const int nb0 = (n0 + wn) >> 4;

  f32x4 acc[4][2];
#pragma unroll
  for (int i = 0; i < 4; ++i)
#pragma unroll
    for (int j = 0; j < 2; ++j) acc[i][j] = (f32x4){0.f, 0.f, 0.f, 0.f};

  uint4 r0, r1;
  r0 = *(const uint4*)(arow_g);
  r1 = *(const uint4*)(arow_g + 8);
  *(uint4*)&Ab[0][sr][sp] = r0;
  *(uint4*)&Ab[0][sr][sp + 8] = r1;
  __syncthreads();

  for (int kb = 0; kb < 16; ++kb) {
    const int cur = kb & 1, nxt = cur ^ 1;
    if (kb < 15) {
      const ushort_t* p = arow_g + (kb + 1) * 32;
      r0 = *(const uint4*)p;
      r1 = *(const uint4*)(p + 8);
    }
    bf16x8 Bf[2];
#pragma unroll
    for (int nt = 0; nt < 2; ++nt)
      Bf[nt] = *(const bf16x8*)&bp[(((size_t)(nb0 + nt) * 16 + kb) * 64 + l63) * 8];
    bf16x8 Af[4];
#pragma unroll
    for (int mt = 0; mt < 4; ++mt)
      Af[mt] = *(const bf16x8*)&Ab[cur][wm + mt * 16 + l16][quad * 8];
#pragma unroll
    for (int mt = 0; mt < 4; ++mt)
#pragma unroll
      for (int nt = 0; nt < 2; ++nt)
        acc[mt][nt] = __builtin_amdgcn_mfma_f32_16x16x32_bf16(
            Af[mt], Bf[nt], acc[mt][nt], 0, 0, 0);
    if (kb < 15) {
      *(uint4*)&Ab[nxt][sr][sp] = r0;
      *(uint4*)&Ab[nxt][sr][sp + 8] = r1;
    }
    __syncthreads();
  }

  // ---- epilogue 1: write Bpack in B-fragment order (bf16) ----
#pragma unroll
  for (int mt = 0; mt < 4; ++mt)
#pragma unroll
    for (int nt = 0; nt < 2; ++nt)
#pragma unroll
      for (int rg = 0; rg < 4; ++rg) {
        int j = m0 + wm + mt * 16 + quad * 4 + rg;
        int c = n0 + wn + nt * 16 + l16;
        int kblk = j >> 5;
        int laneb = ((j >> 3) & 3) * 16 + (c & 15);
        int e = j & 7;
        Bpack[(((size_t)head * 256 + kblk) * 16 + (c >> 4)) * 512 + laneb * 8 + e] =
            f2bf(acc[mt][nt][rg]);
      }
  // ---- epilogue 2: s1/s2 partial dots, shuffle-reduced over 16 cols ----
  float a1v[2], a2v[2];
#pragma unroll
  for (int nt = 0; nt < 2; ++nt) {
    int c = n0 + wn + nt * 16 + l16;
    a1v[nt] = a1[head * 256 + c];
    a2v[nt] = a2[head * 256 + c];
  }
#pragma unroll
  for (int mt = 0; mt < 4; ++mt)
#pragma unroll
    for (int rg = 0; rg < 4; ++rg) {
      float p1 = acc[mt][0][rg] * a1v[0] + acc[mt][1][rg] * a1v[1];
      float p2 = acc[mt][0][rg] * a2v[0] + acc[mt][1][rg] * a2v[1];
      p1 += __shfl_xor(p1, 1); p2 += __shfl_xor(p2, 1);
      p1 += __shfl_xor(p1, 2); p2 += __shfl_xor(p2, 2);
      p1 += __shfl_xor(p1, 4); p2 += __shfl_xor(p2, 4);
      p1 += __shfl_xor(p1, 8); p2 += __shfl_xor(p2, 8);
      if (l16 == 0) {
        int row = m0 + wm + mt * 16 + quad * 4 + rg;
        atomicAdd(&s1[head * 8192 + row], p1);
        atomicAdd(&s2[head * 8192 + row], p2);
      }
    }
}

// ---------------------------------------------------------------------------
// Pipelined split-bf16 MLP GEMM (R9, frozen).
// ---------------------------------------------------------------------------
__global__ __launch_bounds__(256, 2) void gemm_mlp(
    const ushort_t* __restrict__ Ahi, const ushort_t* __restrict__ Alo,
    const ushort_t* __restrict__ Bph, const ushort_t* __restrict__ Bpl,
    const float* __restrict__ bias, float* __restrict__ Cf,
    ushort_t* __restrict__ Chi, ushort_t* __restrict__ Clo,
    int M, int N, int K, float slope)
{
  __shared__ ushort_t Ah[2][128][40], Al[2][128][40];
  const int kbc = K >> 5;
  const int t = threadIdx.x;
  const int m0 = blockIdx.y * 128;
  const int n0 = blockIdx.x * 64;
  const int wave = t >> 6;
  const int wm = (wave & 1) * 64, wn = (wave >> 1) * 32;
  const int l16 = t & 15, quad = (t >> 4) & 3, l63 = t & 63;
  const int sr = t >> 1, sp = (t & 1) * 16;
  const ushort_t* ah_g = Ahi + (size_t)(m0 + sr) * K + sp;
  const ushort_t* al_g = Alo + (size_t)(m0 + sr) * K + sp;
  const int nb0 = (n0 + wn) >> 4;

  f32x4 acc[4][2];
#pragma unroll
  for (int i = 0; i < 4; ++i)
#pragma unroll
    for (int j = 0; j < 2; ++j) acc[i][j] = (f32x4){0.f, 0.f, 0.f, 0.f};

  uint4 rh0, rh1, rl0, rl1;
  rh0 = *(const uint4*)(ah_g);
  rh1 = *(const uint4*)(ah_g + 8);
  rl0 = *(const uint4*)(al_g);
  rl1 = *(const uint4*)(al_g + 8);
  *(uint4*)&Ah[0][sr][sp] = rh0;
  *(uint4*)&Ah[0][sr][sp + 8] = rh1;
  *(uint4*)&Al[0][sr][sp] = rl0;
  *(uint4*)&Al[0][sr][sp + 8] = rl1;
  __syncthreads();

  for (int kb = 0; kb < kbc; ++kb) {
    const int cur = kb & 1, nxt = cur ^ 1;
    if (kb + 1 < kbc) {
      const ushort_t* ph = ah_g + (kb + 1) * 32;
      const ushort_t* plo = al_g + (kb + 1) * 32;
      rh0 = *(const uint4*)ph;
      rh1 = *(const uint4*)(ph + 8);
      rl0 = *(const uint4*)plo;
      rl1 = *(const uint4*)(plo + 8);
    }
    bf16x8 bh[2], bl[2];
#pragma unroll
    for (int nt = 0; nt < 2; ++nt) {
      size_t o = (((size_t)(nb0 + nt) * kbc + kb) * 64 + l63) * 8;
      bh[nt] = *(const bf16x8*)&Bph[o];
      bl[nt] = *(const bf16x8*)&Bpl[o];
    }
    bf16x8 afh[4], afl[4];
#pragma unroll
    for (int mt = 0; mt < 4; ++mt) {
      afh[mt] = *(const bf16x8*)&Ah[cur][wm + mt * 16 + l16][quad * 8];
      afl[mt] = *(const bf16x8*)&Al[cur][wm + mt * 16 + l16][quad * 8];
    }
#pragma unroll
    for (int mt = 0; mt < 4; ++mt)
#pragma unroll
      for (int nt = 0; nt < 2; ++nt) {
        acc[mt][nt] = __builtin_amdgcn_mfma_f32_16x16x32_bf16(afh[mt], bh[nt], acc[mt][nt], 0, 0, 0);
        acc[mt][nt] = __builtin_amdgcn_mfma_f32_16x16x32_bf16(afh[mt], bl[nt], acc[mt][nt], 0, 0, 0);
        acc[mt][nt] = __builtin_amdgcn_mfma_f32_16x16x32_bf16(afl[mt], bh[nt], acc[mt][nt], 0, 0, 0);
      }
    if (kb + 1 < kbc) {
      *(uint4*)&Ah[nxt][sr][sp] = rh0;
      *(uint4*)&Ah[nxt][sr][sp + 8] = rh1;
      *(uint4*)&Al[nxt][sr][sp] = rl0;
      *(uint4*)&Al[nxt][sr][sp + 8] = rl1;
    }
    __syncthreads();
  }

#pragma unroll
  for (int mt = 0; mt < 4; ++mt)
#pragma unroll
    for (int nt = 0; nt < 2; ++nt)
#pragma unroll
      for (int rg = 0; rg < 4; ++rg) {
        int m = m0 + wm + mt * 16 + quad * 4 + rg;
        int n = n0 + wn + nt * 16 + l16;
        float v = lrelu(acc[mt][nt][rg] + bias[n], slope);
        size_t o = (size_t)m * N + n;
        if (Cf) Cf[o] = v;
        if (Chi) {
          ushort_t h = f2bf(v);
          Chi[o] = h; Clo[o] = f2bf(v - bf2f(h));
        }
      }
}

// ---------------------------------------------------------------------------
// MFMA attention v14: EXACT R1 (v8) structure -- 64x4 grid, 1 block/CU,
// LDS exchange + per-kt barrier (R3-R6 proved every structural change
// neutral-to-worse). Single change: gen's exp/lrelu replaced by SEPARABLE
// TABLES. exp(lrelu(s1+s2)) = (s1+s2>0) ? e^s1*e^s2 : e^(a*s1)*e^(a*s2),
// and sign(s1+s2) == (e^s2 > e^-s1). Per-lane hoisted E1/Ea1/T1; per-col
// tables E2=exp(s2), Ea2=exp(a*s2) from exp_tabs (L2-resident, 128KB).
// Inner loop: cmp + 2 cndmask + mul + mask-select -- no v_exp, no lrelu
// (134M exps -> 32K). Targets the measured top pipe (VALUBusy 28% >
// MfmaUtil 17%); gen VALU and MFMA serialize in the lockstep phases.
// ---------------------------------------------------------------------------
__global__ __launch_bounds__(512, 1) void attn_mfma8(
    const ushort_t* __restrict__ Bpack, const float* __restrict__ s1g,
    const float* __restrict__ e2g, const float* __restrict__ ea2g,
    const int* __restrict__ adj,
    ushort_t* __restrict__ pacc, float* __restrict__ pl)
{
  __shared__ ushort_t Wlds[2][2][8][64][8];   // [buf][head][mt8][lane][8]
  const int t = threadIdx.x;
  const int i0 = blockIdx.x * 128;
  const int js = blockIdx.y;
  const int kbase = js * 2048;
  // generator mapping: row wr (0..127), k-octet kq (0..3)
  const int wr = t >> 2, kq = t & 3;
  const int glane = kq * 16 + (wr & 15);
  const int gmt = wr >> 4;                    // 0..7
  const float s1v0 = s1g[i0 + wr];
  const float s1v1 = s1g[8192 + i0 + wr];
  // hoisted separable-exp scalars (6 exps per thread, once)
  const float E10 = __expf(s1v0), Ea10 = __expf(ALPHA * s1v0), T10 = __expf(-s1v0);
  const float E11 = __expf(s1v1), Ea11 = __expf(ALPHA * s1v1), T11 = __expf(-s1v1);
  // consumer mapping: wave = (head, nh, rowgrp)
  const int wave = t >> 6;
  const int head = wave >> 2, nh = (wave >> 1) & 1, rg2 = wave & 1;
  const int l16 = t & 15, quad = (t >> 4) & 3;
  const int l63 = t & 63;
  f32x4 acc[4][8];
#pragma unroll
  for (int m = 0; m < 4; ++m)
#pragma unroll
    for (int n = 0; n < 8; ++n) acc[m][n] = (f32x4){0.f, 0.f, 0.f, 0.f};
  float rs0 = 0.f, rs1 = 0.f;

  const int* arow = adj + (size_t)(i0 + wr) * 8192;
  int4 pa0, pa1;
  float4 e20a, e20b, e21a, e21b;   // E2 tables, head0/head1
  float4 a20a, a20b, a21a, a21b;   // Ea2 tables

  auto fetch = [&](int kk) {
    pa0 = *(const int4*)&arow[kk];
    pa1 = *(const int4*)&arow[kk + 4];
    e20a = *(const float4*)&e2g[kk];
    e20b = *(const float4*)&e2g[kk + 4];
    e21a = *(const float4*)&e2g[8192 + kk];
    e21b = *(const float4*)&e2g[8192 + kk + 4];
    a20a = *(const float4*)&ea2g[kk];
    a20b = *(const float4*)&ea2g[kk + 4];
    a21a = *(const float4*)&ea2g[8192 + kk];
    a21b = *(const float4*)&ea2g[8192 + kk + 4];
  };
  auto gen = [&](int buf) {
    int am[8] = {pa0.x, pa0.y, pa0.z, pa0.w, pa1.x, pa1.y, pa1.z, pa1.w};
    float E20[8] = {e20a.x, e20a.y, e20a.z, e20a.w, e20b.x, e20b.y, e20b.z, e20b.w};
    float E21[8] = {e21a.x, e21a.y, e21a.z, e21a.w, e21b.x, e21b.y, e21b.z, e21b.w};
    float A20[8] = {a20a.x, a20a.y, a20a.z, a20a.w, a20b.x, a20b.y, a20b.z, a20b.w};
    float A21[8] = {a21a.x, a21a.y, a21a.z, a21a.w, a21b.x, a21b.y, a21b.z, a21b.w};
    ushort_t w0[8] __attribute__((aligned(16)));
    ushort_t w1[8] __attribute__((aligned(16)));
#pragma unroll
    for (int e = 0; e < 8; ++e) {
      bool p0 = E20[e] > T10;
      bool p1 = E21[e] > T11;
      float v0 = (p0 ? E10 : Ea10) * (p0 ? E20[e] : A20[e]);
      float v1 = (p1 ? E11 : Ea11) * (p1 ? E21[e] : A21[e]);
      v0 = am[e] > 0 ? v0 : 0.f;
      v1 = am[e] > 0 ? v1 : 0.f;
      rs0 += v0; rs1 += v1;
      w0[e] = f2bf(v0); w1[e] = f2bf(v1);
    }
    *(uint4*)&Wlds[buf][0][gmt][glane][0] = *(uint4*)w0;
    *(uint4*)&Wlds[buf][1][gmt][glane][0] = *(uint4*)w1;
  };

  fetch(kbase + kq * 8);
  gen(0);
  fetch(kbase + 32 + kq * 8);
  ASM_BARRIER();

  for (int kt = 0; kt < 64; ++kt) {
    const int cur = kt & 1, nxt = cur ^ 1;
    const int kblk = js * 64 + kt;
    const ushort_t* bb =
        Bpack + ((((size_t)head * 256 + kblk) * 16 + nh * 8) * 64 + l63) * 8;
    bf16x8 Bf[8];
#pragma unroll
    for (int nt = 0; nt < 8; ++nt)
      Bf[nt] = *(const bf16x8*)&bb[nt * 512];
    bf16x8 Af[4];
#pragma unroll
    for (int mt = 0; mt < 4; ++mt)
      Af[mt] = *(const bf16x8*)&Wlds[cur][head][rg2 * 4 + mt][l63][0];
#pragma unroll
    for (int mt = 0; mt < 4; ++mt)
#pragma unroll
      for (int nt = 0; nt < 8; ++nt)
        acc[mt][nt] = __builtin_amdgcn_mfma_f32_16x16x32_bf16(
            Af[mt], Bf[nt], acc[mt][nt], 0, 0, 0);
    if (kt < 63) {
      gen(nxt);
      if (kt < 62) fetch(kbase + (kt + 2) * 32 + kq * 8);
    }
    ASM_BARRIER();
  }

  // denominators: reduce across the 4 kq lanes of each row
  rs0 += __shfl_xor(rs0, 1); rs0 += __shfl_xor(rs0, 2);
  rs1 += __shfl_xor(rs1, 1); rs1 += __shfl_xor(rs1, 2);
  if (kq == 0) {
    pl[((size_t)js * 2 + 0) * 8192 + i0 + wr] = rs0;
    pl[((size_t)js * 2 + 1) * 8192 + i0 + wr] = rs1;
  }
  // store bf16 partial numerators
  const int n0 = nh * 128;
#pragma unroll
  for (int mt = 0; mt < 4; ++mt)
#pragma unroll
    for (int nt = 0; nt < 8; ++nt)
#pragma unroll
      for (int rg = 0; rg < 4; ++rg) {
        int row = i0 + rg2 * 64 + mt * 16 + quad * 4 + rg;
        int col = n0 + nt * 16 + l16;
        pacc[(((size_t)js * 2 + head) * 8192 + row) * 256 + col] =
            f2bf(acc[mt][nt][rg]);
      }
}

// ---------------------------------------------------------------------------
// Finalize (R9, frozen): emits embed directly as hi/lo bf16 split.
// ---------------------------------------------------------------------------
__global__ __launch_bounds__(256) void attn_finalize(
    const ushort_t* __restrict__ pacc, const float* __restrict__ pl,
    const float* __restrict__ bg, const float* __restrict__ llm,
    ushort_t* __restrict__ ehi, ushort_t* __restrict__ elo)
{
  __shared__ float red[8];
  const int r = blockIdx.x;
  const int t = threadIdx.x;
  const int wv = t >> 6, lane = t & 63;
#pragma unroll
  for (int half = 0; half < 2; ++half) {
    float lv = llm[(size_t)r * 512 + half * 256 + t];
    ushort_t h = f2bf(lv);
    ehi[(size_t)r * 768 + half * 256 + t] = h;
    elo[(size_t)r * 768 + half * 256 + t] = f2bf(lv - bf2f(h));
  }
  float o[2];
#pragma unroll
  for (int hh = 0; hh < 2; ++hh) {
    float num = 0.f, l = 0.f;
#pragma unroll
    for (int js = 0; js < 4; ++js) {
      num += bf2f(pacc[(((size_t)js * 2 + hh) * 8192 + r) * 256 + t]);
      l += pl[((size_t)js * 2 + hh) * 8192 + r];
    }
    o[hh] = lrelu(num / l, ALPHA);
  }
  float v0 = o[0] * o[0], v1 = o[1] * o[1];
  for (int off = 32; off > 0; off >>= 1) {
    v0 += __shfl_xor(v0, off);
    v1 += __shfl_xor(v1, off);
  }
  if (lane == 0) { red[wv] = v0; red[4 + wv] = v1; }
  __syncthreads();
  float n0 = fmaxf(sqrtf(red[0] + red[1] + red[2] + red[3]), 1e-12f);
  float n1 = fmaxf(sqrtf(red[4] + red[5] + red[6] + red[7]), 1e-12f);
  float val = 0.5f * (o[0] / n0 + bg[t] + o[1] / n1 + bg[256 + t]);
  ushort_t h = f2bf(val);
  ehi[(size_t)r * 768 + 512 + t] = h;
  elo[(size_t)r * 768 + 512 + t] = f2bf(val - bf2f(h));
}

// ---------------------------------------------------------------------------
__global__ __launch_bounds__(256) void pred_kernel(
    const float* __restrict__ z2, const int* __restrict__ ts,
    float* __restrict__ out, int E)
{
  const int gw = (blockIdx.x * 256 + threadIdx.x) >> 6;
  const int lane = threadIdx.x & 63;
  if (gw >= E) return;
  const int a = ts[gw * 2], b = ts[gw * 2 + 1];
  float4 va = ((const float4*)(z2 + (size_t)a * 256))[lane];
  float4 vb = ((const float4*)(z2 + (size_t)b * 256))[lane];
  float p = va.x * vb.x + va.y * vb.y + va.z * vb.z + va.w * vb.w;
  for (int off = 32; off > 0; off >>= 1) p += __shfl_xor(p, off);
  if (lane == 0) out[gw] = p;
}

// ---------------------------------------------------------------------------
extern "C" void kernel_launch(void* const* d_in, const int* in_sizes, int n_in,
                              void* d_out, int out_size, void* d_ws, size_t ws_size,
                              hipStream_t stream) {
  const float* x   = (const float*)d_in[0];
  const int*   adj = (const int*)d_in[1];
  const int*   ts  = (const int*)d_in[2];
  const float* llm = (const float*)d_in[3];
  const float* Wg  = (const float*)d_in[4];
  const float* a1  = (const float*)d_in[5];
  const float* a2  = (const float*)d_in[6];
  const float* bg  = (const float*)d_in[7];
  const float* W1  = (const float*)d_in[8];
  const float* b1  = (const float*)d_in[9];
  const float* W2  = (const float*)d_in[10];
  const float* b2  = (const float*)d_in[11];
  float* out = (float*)d_out;
  float* ws  = (float*)d_ws;
  const int E = in_sizes[2] / 2;

  // ---- workspace layout (float words) ----
  ushort_t* xb    = (ushort_t*)(ws + 0);            //  8192x512 bf16
  ushort_t* Wgp   = (ushort_t*)(ws + 2097152);      //  2x512x256
  ushort_t* W1ph  = (ushort_t*)(ws + 2228224);      //  768x512
  ushort_t* W1pl  = (ushort_t*)(ws + 2424832);
  ushort_t* W2ph  = (ushort_t*)(ws + 2621440);      //  512x256
  ushort_t* W2pl  = (ushort_t*)(ws + 2686976);
  ushort_t* Bpack = (ushort_t*)(ws + 2752512);      //  2x8192x256
  float*    s1    = ws + 4849664;                   //  2x8192
  float*    s2    = ws + 4866048;
  float*    pl    = ws + 4882432;                   //  8x8192
  ushort_t* pacc  = (ushort_t*)(ws + 4947968);      //  8x8192x256
  ushort_t* ehi   = (ushort_t*)(ws + 13336576);     //  8192x768
  ushort_t* elo   = (ushort_t*)(ws + 16482304);
  ushort_t* z1hi  = (ushort_t*)(ws + 19628032);     //  8192x512
  ushort_t* z1lo  = (ushort_t*)(ws + 21725184);
  float*    z2    = ws + 23822336;                  //  8192x256 f32
  float*    e2t   = ws + 25919488;                  //  2x8192 exp(s2)
  float*    ea2t  = ws + 25935872;                  //  2x8192 exp(a*s2)

  // 1. prep: casts, weight packing, s-zero
  tobf<<<4096, 256, 0, stream>>>(x, xb);
  pack_wt<<<dim3(64, 2), 256, 0, stream>>>(Wg, Wgp, nullptr, 512, 256);
  pack_wt<<<dim3(192, 1), 256, 0, stream>>>(W1, W1ph, W1pl, 768, 512);
  pack_wt<<<dim3(64, 1), 256, 0, stream>>>(W2, W2ph, W2pl, 512, 256);
  zero_f<<<32, 256, 0, stream>>>(s1);   // covers s1 and s2 (contiguous)
  // 2. fused h-GEMM -> Bpack + s1/s2 (hbuf never materialized)
  gemm_h<<<dim3(4, 64, 2), 256, 0, stream>>>(xb, Wgp, a1, a2, Bpack, s1, s2);
  // 2b. separable-exp tables from s2 (both heads contiguous)
  exp_tabs<<<64, 256, 0, stream>>>(s2, e2t, ea2t);
  // 3. MFMA attention partials (R1 structure, table-based gen)
  attn_mfma8<<<dim3(64, 4), 512, 0, stream>>>(Bpack, s1, e2t, ea2t, adj, pacc, pl);
  // 4. finalize -> embed emitted directly as hi/lo split (llm inline)
  attn_finalize<<<8192, 256, 0, stream>>>(pacc, pl, bg, llm, ehi, elo);
  // 5. z1 = LR(embed @ W1 + b1) -> hi/lo
  gemm_mlp<<<dim3(8, 64), 256, 0, stream>>>(
      ehi, elo, W1ph, W1pl, b1, nullptr, z1hi, z1lo, 8192, 512, 768, MLP_SLOPE);
  // 6. z2 = LR(z1 @ W2 + b2) -> fp32
  gemm_mlp<<<dim3(4, 64), 256, 0, stream>>>(
      z1hi, z1lo, W2ph, W2pl, b2, z2, nullptr, nullptr, 8192, 256, 512, MLP_SLOPE);
  // 7. edge dots
  pred_kernel<<<(E * 64 + 255) / 256, 256, 0, stream>>>(z2, ts, out, E);
}

// Round 8
// 575.995 us; speedup vs baseline: 1.1453x; 1.0399x over previous
//
#include <hip/hip_runtime.h>
#include <hip/hip_bf16.h>
#include <cstdint>
#include <cstddef>

#define ALPHA 0.2f
#define MLP_SLOPE 0.01f

typedef short bf16x8 __attribute__((ext_vector_type(8)));
typedef float f32x4 __attribute__((ext_vector_type(4)));
typedef unsigned short ushort_t;

// raw barrier: syncs LDS exchange WITHOUT draining vmcnt (global prefetches
// stay in flight across it).
#define ASM_BARRIER() __asm__ __volatile__("s_waitcnt lgkmcnt(0)\n\ts_barrier" ::: "memory")

__device__ __forceinline__ float lrelu(float x, float s) { return x > 0.f ? x : x * s; }
__device__ __forceinline__ ushort_t f2bf(float x) {
  __hip_bfloat16 h = __float2bfloat16(x);
  return *reinterpret_cast<ushort_t*>(&h);
}
__device__ __forceinline__ float bf2f(ushort_t u) {
  union { unsigned int i; float f; } v; v.i = ((unsigned int)u) << 16; return v.f;
}

// ---------------------------------------------------------------------------
// pack body: W[K,N] (batch offset b) into MFMA B-fragment order.
// ---------------------------------------------------------------------------
__device__ __forceinline__ void pack_body(
    const float* __restrict__ W, ushort_t* __restrict__ hi,
    ushort_t* __restrict__ lo, int K, int N, int gid, int batch)
{
  int lane = gid & 63;
  int kbc = K >> 5;
  int kblk = (gid >> 6) % kbc;
  int nblk = (gid >> 6) / kbc;
  size_t b = (size_t)batch * K * N;
  int col = nblk * 16 + (lane & 15);
  int krow = kblk * 32 + (lane >> 4) * 8;
  ushort_t h[8] __attribute__((aligned(16)));
  ushort_t l[8] __attribute__((aligned(16)));
#pragma unroll
  for (int e = 0; e < 8; ++e) {
    float v = W[b + (size_t)(krow + e) * N + col];
    h[e] = f2bf(v);
    l[e] = f2bf(v - bf2f(h[e]));
  }
  *(uint4*)&hi[b + (size_t)gid * 8] = *(uint4*)h;
  if (lo) *(uint4*)&lo[b + (size_t)gid * 8] = *(uint4*)l;
}

// ---------------------------------------------------------------------------
// prep_all: fuses tobf (4096 blocks) + pack Wg (128) + pack W1 (192) +
// pack W2 (64) + zero s1/s2 (32) into ONE launch = 4512 blocks.
// Whole blocks take one role -> no intra-wave divergence; math identical
// to the 5 original kernels. Saves 4 stream-serialized launch gaps.
// ---------------------------------------------------------------------------
__global__ __launch_bounds__(256) void prep_all(
    const float* __restrict__ x, ushort_t* __restrict__ xb,
    const float* __restrict__ Wg, ushort_t* __restrict__ Wgp,
    const float* __restrict__ W1, ushort_t* __restrict__ W1ph,
    ushort_t* __restrict__ W1pl,
    const float* __restrict__ W2, ushort_t* __restrict__ W2ph,
    ushort_t* __restrict__ W2pl, float* __restrict__ s12)
{
  const int b = blockIdx.x;
  const int t = threadIdx.x;
  if (b < 4096) {                       // tobf: x -> xb (bf16), 4 elems/thread
    int idx = b * 256 + t;
    float4 v = ((const float4*)x)[idx];
    ushort4 h;
    h.x = f2bf(v.x); h.y = f2bf(v.y); h.z = f2bf(v.z); h.w = f2bf(v.w);
    ((ushort4*)xb)[idx] = h;
  } else if (b < 4224) {                // pack Wg (2 heads x 64 blocks)
    int local = b - 4096;
    pack_body(Wg, Wgp, nullptr, 512, 256, (local & 63) * 256 + t, local >> 6);
  } else if (b < 4416) {                // pack W1 hi/lo
    int local = b - 4224;
    pack_body(W1, W1ph, W1pl, 768, 512, local * 256 + t, 0);
  } else if (b < 4480) {                // pack W2 hi/lo
    int local = b - 4416;
    pack_body(W2, W2ph, W2pl, 512, 256, local * 256 + t, 0);
  } else {                              // zero s1+s2 (contiguous 32768 floats)
    int idx = (b - 4480) * 256 + t;
    ((float4*)s12)[idx] = make_float4(0.f, 0.f, 0.f, 0.f);
  }
}

// ---------------------------------------------------------------------------
// Fused h-GEMM: h = x@Wg (single-pass bf16), epilogue writes Bpack (B-frag
// order) + atomic s1/s2 dots. h never materialized in fp32.  (R9, frozen)
// ---------------------------------------------------------------------------
__global__ __launch_bounds__(256, 2) void gemm_h(
    const ushort_t* __restrict__ xb, const ushort_t* __restrict__ Wgp,
    const float* __restrict__ a1, const float* __restrict__ a2,
    ushort_t* __restrict__ Bpack, float* __restrict__ s1,
    float* __restrict__ s2)
{
  __shared__ ushort_t Ab[2][128][40];
  const int t = threadIdx.x;
  const int head = blockIdx.z;
  const int m0 = blockIdx.y * 128;
  const int n0 = blockIdx.x * 64;
  const int wave = t >> 6;
  const int wm = (wave & 1) * 64, wn = (wave >> 1) * 32;
  const int l16 = t & 15, quad = (t >> 4) & 3, l63 = t & 63;
  const int sr = t >> 1, sp = (t & 1) * 16;
  const ushort_t* arow_g = xb + (size_t)(m0 + sr) * 512 + sp;
  const ushort_t* bp = Wgp + (size_t)head * 256 * 512;
  const int nb0 = (n0 + wn) >> 4;

  f32x4 acc[4][2];
#pragma unroll
  for (int i = 0; i < 4; ++i)
#pragma unroll
    for (int j = 0; j < 2; ++j) acc[i][j] = (f32x4){0.f, 0.f, 0.f, 0.f};

  uint4 r0, r1;
  r0 = *(const uint4*)(arow_g);
  r1 = *(const uint4*)(arow_g + 8);
  *(uint4*)&Ab[0][sr][sp] = r0;
  *(uint4*)&Ab[0][sr][sp + 8] = r1;
  __syncthreads();

  for (int kb = 0; kb < 16; ++kb) {
    const int cur = kb & 1, nxt = cur ^ 1;
    if (kb < 15) {
      const ushort_t* p = arow_g + (kb + 1) * 32;
      r0 = *(const uint4*)p;
      r1 = *(const uint4*)(p + 8);
    }
    bf16x8 Bf[2];
#pragma unroll
    for (int nt = 0; nt < 2; ++nt)
      Bf[nt] = *(const bf16x8*)&bp[(((size_t)(nb0 + nt) * 16 + kb) * 64 + l63) * 8];
    bf16x8 Af[4];
#pragma unroll
    for (int mt = 0; mt < 4; ++mt)
      Af[mt] = *(const bf16x8*)&Ab[cur][wm + mt * 16 + l16][quad * 8];
#pragma unroll
    for (int mt = 0; mt < 4; ++mt)
#pragma unroll
      for (int nt = 0; nt < 2; ++nt)
        acc[mt][nt] = __builtin_amdgcn_mfma_f32_16x16x32_bf16(
            Af[mt], Bf[nt], acc[mt][nt], 0, 0, 0);
    if (kb < 15) {
      *(uint4*)&Ab[nxt][sr][sp] = r0;
      *(uint4*)&Ab[nxt][sr][sp + 8] = r1;
    }
    __syncthreads();
  }

  // ---- epilogue 1: write Bpack in B-fragment order (bf16) ----
#pragma unroll
  for (int mt = 0; mt < 4; ++mt)
#pragma unroll
    for (int nt = 0; nt < 2; ++nt)
#pragma unroll
      for (int rg = 0; rg < 4; ++rg) {
        int j = m0 + wm + mt * 16 + quad * 4 + rg;
        int c = n0 + wn + nt * 16 + l16;
        int kblk = j >> 5;
        int laneb = ((j >> 3) & 3) * 16 + (c & 15);
        int e = j & 7;
        Bpack[(((size_t)head * 256 + kblk) * 16 + (c >> 4)) * 512 + laneb * 8 + e] =
            f2bf(acc[mt][nt][rg]);
      }
  // ---- epilogue 2: s1/s2 partial dots, shuffle-reduced over 16 cols ----
  float a1v[2], a2v[2];
#pragma unroll
  for (int nt = 0; nt < 2; ++nt) {
    int c = n0 + wn + nt * 16 + l16;
    a1v[nt] = a1[head * 256 + c];
    a2v[nt] = a2[head * 256 + c];
  }
#pragma unroll
  for (int mt = 0; mt < 4; ++mt)
#pragma unroll
    for (int rg = 0; rg < 4; ++rg) {
      float p1 = acc[mt][0][rg] * a1v[0] + acc[mt][1][rg] * a1v[1];
      float p2 = acc[mt][0][rg] * a2v[0] + acc[mt][1][rg] * a2v[1];
      p1 += __shfl_xor(p1, 1); p2 += __shfl_xor(p2, 1);
      p1 += __shfl_xor(p1, 2); p2 += __shfl_xor(p2, 2);
      p1 += __shfl_xor(p1, 4); p2 += __shfl_xor(p2, 4);
      p1 += __shfl_xor(p1, 8); p2 += __shfl_xor(p2, 8);
      if (l16 == 0) {
        int row = m0 + wm + mt * 16 + quad * 4 + rg;
        atomicAdd(&s1[head * 8192 + row], p1);
        atomicAdd(&s2[head * 8192 + row], p2);
      }
    }
}

// ---------------------------------------------------------------------------
// Pipelined split-bf16 MLP GEMM (R9, frozen).
// ---------------------------------------------------------------------------
__global__ __launch_bounds__(256, 2) void gemm_mlp(
    const ushort_t* __restrict__ Ahi, const ushort_t* __restrict__ Alo,
    const ushort_t* __restrict__ Bph, const ushort_t* __restrict__ Bpl,
    const float* __restrict__ bias, float* __restrict__ Cf,
    ushort_t* __restrict__ Chi, ushort_t* __restrict__ Clo,
    int M, int N, int K, float slope)
{
  __shared__ ushort_t Ah[2][128][40], Al[2][128][40];
  const int kbc = K >> 5;
  const int t = threadIdx.x;
  const int m0 = blockIdx.y * 128;
  const int n0 = blockIdx.x * 64;
  const int wave = t >> 6;
  const int wm = (wave & 1) * 64, wn = (wave >> 1) * 32;
  const int l16 = t & 15, quad = (t >> 4) & 3, l63 = t & 63;
  const int sr = t >> 1, sp = (t & 1) * 16;
  const ushort_t* ah_g = Ahi + (size_t)(m0 + sr) * K + sp;
  const ushort_t* al_g = Alo + (size_t)(m0 + sr) * K + sp;
  const int nb0 = (n0 + wn) >> 4;

  f32x4 acc[4][2];
#pragma unroll
  for (int i = 0; i < 4; ++i)
#pragma unroll
    for (int j = 0; j < 2; ++j) acc[i][j] = (f32x4){0.f, 0.f, 0.f, 0.f};

  uint4 rh0, rh1, rl0, rl1;
  rh0 = *(const uint4*)(ah_g);
  rh1 = *(const uint4*)(ah_g + 8);
  rl0 = *(const uint4*)(al_g);
  rl1 = *(const uint4*)(al_g + 8);
  *(uint4*)&Ah[0][sr][sp] = rh0;
  *(uint4*)&Ah[0][sr][sp + 8] = rh1;
  *(uint4*)&Al[0][sr][sp] = rl0;
  *(uint4*)&Al[0][sr][sp + 8] = rl1;
  __syncthreads();

  for (int kb = 0; kb < kbc; ++kb) {
    const int cur = kb & 1, nxt = cur ^ 1;
    if (kb + 1 < kbc) {
      const ushort_t* ph = ah_g + (kb + 1) * 32;
      const ushort_t* plo = al_g + (kb + 1) * 32;
      rh0 = *(const uint4*)ph;
      rh1 = *(const uint4*)(ph + 8);
      rl0 = *(const uint4*)plo;
      rl1 = *(const uint4*)(plo + 8);
    }
    bf16x8 bh[2], bl[2];
#pragma unroll
    for (int nt = 0; nt < 2; ++nt) {
      size_t o = (((size_t)(nb0 + nt) * kbc + kb) * 64 + l63) * 8;
      bh[nt] = *(const bf16x8*)&Bph[o];
      bl[nt] = *(const bf16x8*)&Bpl[o];
    }
    bf16x8 afh[4], afl[4];
#pragma unroll
    for (int mt = 0; mt < 4; ++mt) {
      afh[mt] = *(const bf16x8*)&Ah[cur][wm + mt * 16 + l16][quad * 8];
      afl[mt] = *(const bf16x8*)&Al[cur][wm + mt * 16 + l16][quad * 8];
    }
#pragma unroll
    for (int mt = 0; mt < 4; ++mt)
#pragma unroll
      for (int nt = 0; nt < 2; ++nt) {
        acc[mt][nt] = __builtin_amdgcn_mfma_f32_16x16x32_bf16(afh[mt], bh[nt], acc[mt][nt], 0, 0, 0);
        acc[mt][nt] = __builtin_amdgcn_mfma_f32_16x16x32_bf16(afh[mt], bl[nt], acc[mt][nt], 0, 0, 0);
        acc[mt][nt] = __builtin_amdgcn_mfma_f32_16x16x32_bf16(afl[mt], bh[nt], acc[mt][nt], 0, 0, 0);
      }
    if (kb + 1 < kbc) {
      *(uint4*)&Ah[nxt][sr][sp] = rh0;
      *(uint4*)&Ah[nxt][sr][sp + 8] = rh1;
      *(uint4*)&Al[nxt][sr][sp] = rl0;
      *(uint4*)&Al[nxt][sr][sp + 8] = rl1;
    }
    __syncthreads();
  }

#pragma unroll
  for (int mt = 0; mt < 4; ++mt)
#pragma unroll
    for (int nt = 0; nt < 2; ++nt)
#pragma unroll
      for (int rg = 0; rg < 4; ++rg) {
        int m = m0 + wm + mt * 16 + quad * 4 + rg;
        int n = n0 + wn + nt * 16 + l16;
        float v = lrelu(acc[mt][nt][rg] + bias[n], slope);
        size_t o = (size_t)m * N + n;
        if (Cf) Cf[o] = v;
        if (Chi) {
          ushort_t h = f2bf(v);
          Chi[o] = h; Clo[o] = f2bf(v - bf2f(h));
        }
      }
}

// ---------------------------------------------------------------------------
// MFMA attention v8 (R1, twice-verified 584.5/584.4 us): 128-row 512-thread
// blocks, 64x4 grid = 1 block/CU, LDS W-exchange + per-kt lgkm barrier.
// R3-R7 falsified every perturbation: Bf-load staging (neutral), fewer
// barriers (-9%), 2 blocks/CU (-25%), no-barrier self-gen (-45%),
// table-gen VALU cut (-9% despite VALUBusy 28->20). This structure is the
// measured local optimum; do not perturb without a new counter signal.
// ---------------------------------------------------------------------------
__global__ __launch_bounds__(512, 1) void attn_mfma8(
    const ushort_t* __restrict__ Bpack, const float* __restrict__ s1g,
    const float* __restrict__ s2g, const int* __restrict__ adj,
    ushort_t* __restrict__ pacc, float* __restrict__ pl)
{
  __shared__ ushort_t Wlds[2][2][8][64][8];   // [buf][head][mt8][lane][8]
  const int t = threadIdx.x;
  const int i0 = blockIdx.x * 128;
  const int js = blockIdx.y;
  const int kbase = js * 2048;
  // generator mapping: row wr (0..127), k-octet kq (0..3)
  const int wr = t >> 2, kq = t & 3;
  const int glane = kq * 16 + (wr & 15);
  const int gmt = wr >> 4;                    // 0..7
  const float s1v0 = s1g[i0 + wr];
  const float s1v1 = s1g[8192 + i0 + wr];
  // consumer mapping: wave = (head, nh, rowgrp)
  const int wave = t >> 6;
  const int head = wave >> 2, nh = (wave >> 1) & 1, rg2 = wave & 1;
  const int l16 = t & 15, quad = (t >> 4) & 3;
  const int l63 = t & 63;
  f32x4 acc[4][8];
#pragma unroll
  for (int m = 0; m < 4; ++m)
#pragma unroll
    for (int n = 0; n < 8; ++n) acc[m][n] = (f32x4){0.f, 0.f, 0.f, 0.f};
  float rs0 = 0.f, rs1 = 0.f;

  const int* arow = adj + (size_t)(i0 + wr) * 8192;
  int4 pa0, pa1;
  float4 p20a, p20b, p21a, p21b;

  auto fetch = [&](int kk) {
    pa0 = *(const int4*)&arow[kk];
    pa1 = *(const int4*)&arow[kk + 4];
    p20a = *(const float4*)&s2g[kk];
    p20b = *(const float4*)&s2g[kk + 4];
    p21a = *(const float4*)&s2g[8192 + kk];
    p21b = *(const float4*)&s2g[8192 + kk + 4];
  };
  auto gen = [&](int buf) {
    int am[8] = {pa0.x, pa0.y, pa0.z, pa0.w, pa1.x, pa1.y, pa1.z, pa1.w};
    float s20[8] = {p20a.x, p20a.y, p20a.z, p20a.w, p20b.x, p20b.y, p20b.z, p20b.w};
    float s21[8] = {p21a.x, p21a.y, p21a.z, p21a.w, p21b.x, p21b.y, p21b.z, p21b.w};
    ushort_t w0[8] __attribute__((aligned(16)));
    ushort_t w1[8] __attribute__((aligned(16)));
#pragma unroll
    for (int e = 0; e < 8; ++e) {
      float e0 = s1v0 + s20[e];
      float e1 = s1v1 + s21[e];
      e0 = fmaxf(e0, 0.f) + ALPHA * fminf(e0, 0.f);
      e1 = fmaxf(e1, 0.f) + ALPHA * fminf(e1, 0.f);
      float v0 = am[e] > 0 ? __expf(e0) : 0.f;
      float v1 = am[e] > 0 ? __expf(e1) : 0.f;
      rs0 += v0; rs1 += v1;
      w0[e] = f2bf(v0); w1[e] = f2bf(v1);
    }
    *(uint4*)&Wlds[buf][0][gmt][glane][0] = *(uint4*)w0;
    *(uint4*)&Wlds[buf][1][gmt][glane][0] = *(uint4*)w1;
  };

  fetch(kbase + kq * 8);
  gen(0);
  fetch(kbase + 32 + kq * 8);
  ASM_BARRIER();

  for (int kt = 0; kt < 64; ++kt) {
    const int cur = kt & 1, nxt = cur ^ 1;
    const int kblk = js * 64 + kt;
    const ushort_t* bb =
        Bpack + ((((size_t)head * 256 + kblk) * 16 + nh * 8) * 64 + l63) * 8;
    bf16x8 Bf[8];
#pragma unroll
    for (int nt = 0; nt < 8; ++nt)
      Bf[nt] = *(const bf16x8*)&bb[nt * 512];
    bf16x8 Af[4];
#pragma unroll
    for (int mt = 0; mt < 4; ++mt)
      Af[mt] = *(const bf16x8*)&Wlds[cur][head][rg2 * 4 + mt][l63][0];
#pragma unroll
    for (int mt = 0; mt < 4; ++mt)
#pragma unroll
      for (int nt = 0; nt < 8; ++nt)
        acc[mt][nt] = __builtin_amdgcn_mfma_f32_16x16x32_bf16(
            Af[mt], Bf[nt], acc[mt][nt], 0, 0, 0);
    if (kt < 63) {
      gen(nxt);
      if (kt < 62) fetch(kbase + (kt + 2) * 32 + kq * 8);
    }
    ASM_BARRIER();
  }

  // denominators: reduce across the 4 kq lanes of each row
  rs0 += __shfl_xor(rs0, 1); rs0 += __shfl_xor(rs0, 2);
  rs1 += __shfl_xor(rs1, 1); rs1 += __shfl_xor(rs1, 2);
  if (kq == 0) {
    pl[((size_t)js * 2 + 0) * 8192 + i0 + wr] = rs0;
    pl[((size_t)js * 2 + 1) * 8192 + i0 + wr] = rs1;
  }
  // store bf16 partial numerators
  const int n0 = nh * 128;
#pragma unroll
  for (int mt = 0; mt < 4; ++mt)
#pragma unroll
    for (int nt = 0; nt < 8; ++nt)
#pragma unroll
      for (int rg = 0; rg < 4; ++rg) {
        int row = i0 + rg2 * 64 + mt * 16 + quad * 4 + rg;
        int col = n0 + nt * 16 + l16;
        pacc[(((size_t)js * 2 + head) * 8192 + row) * 256 + col] =
            f2bf(acc[mt][nt][rg]);
      }
}

// ---------------------------------------------------------------------------
// Finalize (R9, frozen): emits embed directly as hi/lo bf16 split.
// ---------------------------------------------------------------------------
__global__ __launch_bounds__(256) void attn_finalize(
    const ushort_t* __restrict__ pacc, const float* __restrict__ pl,
    const float* __restrict__ bg, const float* __restrict__ llm,
    ushort_t* __restrict__ ehi, ushort_t* __restrict__ elo)
{
  __shared__ float red[8];
  const int r = blockIdx.x;
  const int t = threadIdx.x;
  const int wv = t >> 6, lane = t & 63;
#pragma unroll
  for (int half = 0; half < 2; ++half) {
    float lv = llm[(size_t)r * 512 + half * 256 + t];
    ushort_t h = f2bf(lv);
    ehi[(size_t)r * 768 + half * 256 + t] = h;
    elo[(size_t)r * 768 + half * 256 + t] = f2bf(lv - bf2f(h));
  }
  float o[2];
#pragma unroll
  for (int hh = 0; hh < 2; ++hh) {
    float num = 0.f, l = 0.f;
#pragma unroll
    for (int js = 0; js < 4; ++js) {
      num += bf2f(pacc[(((size_t)js * 2 + hh) * 8192 + r) * 256 + t]);
      l += pl[((size_t)js * 2 + hh) * 8192 + r];
    }
    o[hh] = lrelu(num / l, ALPHA);
  }
  float v0 = o[0] * o[0], v1 = o[1] * o[1];
  for (int off = 32; off > 0; off >>= 1) {
    v0 += __shfl_xor(v0, off);
    v1 += __shfl_xor(v1, off);
  }
  if (lane == 0) { red[wv] = v0; red[4 + wv] = v1; }
  __syncthreads();
  float n0 = fmaxf(sqrtf(red[0] + red[1] + red[2] + red[3]), 1e-12f);
  float n1 = fmaxf(sqrtf(red[4] + red[5] + red[6] + red[7]), 1e-12f);
  float val = 0.5f * (o[0] / n0 + bg[t] + o[1] / n1 + bg[256 + t]);
  ushort_t h = f2bf(val);
  ehi[(size_t)r * 768 + 512 + t] = h;
  elo[(size_t)r * 768 + 512 + t] = f2bf(val - bf2f(h));
}

// ---------------------------------------------------------------------------
__global__ __launch_bounds__(256) void pred_kernel(
    const float* __restrict__ z2, const int* __restrict__ ts,
    float* __restrict__ out, int E)
{
  const int gw = (blockIdx.x * 256 + threadIdx.x) >> 6;
  const int lane = threadIdx.x & 63;
  if (gw >= E) return;
  const int a = ts[gw * 2], b = ts[gw * 2 + 1];
  float4 va = ((const float4*)(z2 + (size_t)a * 256))[lane];
  float4 vb = ((const float4*)(z2 + (size_t)b * 256))[lane];
  float p = va.x * vb.x + va.y * vb.y + va.z * vb.z + va.w * vb.w;
  for (int off = 32; off > 0; off >>= 1) p += __shfl_xor(p, off);
  if (lane == 0) out[gw] = p;
}

// ---------------------------------------------------------------------------
extern "C" void kernel_launch(void* const* d_in, const int* in_sizes, int n_in,
                              void* d_out, int out_size, void* d_ws, size_t ws_size,
                              hipStream_t stream) {
  const float* x   = (const float*)d_in[0];
  const int*   adj = (const int*)d_in[1];
  const int*   ts  = (const int*)d_in[2];
  const float* llm = (const float*)d_in[3];
  const float* Wg  = (const float*)d_in[4];
  const float* a1  = (const float*)d_in[5];
  const float* a2  = (const float*)d_in[6];
  const float* bg  = (const float*)d_in[7];
  const float* W1  = (const float*)d_in[8];
  const float* b1  = (const float*)d_in[9];
  const float* W2  = (const float*)d_in[10];
  const float* b2  = (const float*)d_in[11];
  float* out = (float*)d_out;
  float* ws  = (float*)d_ws;
  const int E = in_sizes[2] / 2;

  // ---- workspace layout (float words) ----
  ushort_t* xb    = (ushort_t*)(ws + 0);            //  8192x512 bf16
  ushort_t* Wgp   = (ushort_t*)(ws + 2097152);      //  2x512x256
  ushort_t* W1ph  = (ushort_t*)(ws + 2228224);      //  768x512
  ushort_t* W1pl  = (ushort_t*)(ws + 2424832);
  ushort_t* W2ph  = (ushort_t*)(ws + 2621440);      //  512x256
  ushort_t* W2pl  = (ushort_t*)(ws + 2686976);
  ushort_t* Bpack = (ushort_t*)(ws + 2752512);      //  2x8192x256
  float*    s1    = ws + 4849664;                   //  2x8192
  float*    s2    = ws + 4866048;
  float*    pl    = ws + 4882432;                   //  8x8192
  ushort_t* pacc  = (ushort_t*)(ws + 4947968);      //  8x8192x256
  ushort_t* ehi   = (ushort_t*)(ws + 13336576);     //  8192x768
  ushort_t* elo   = (ushort_t*)(ws + 16482304);
  ushort_t* z1hi  = (ushort_t*)(ws + 19628032);     //  8192x512
  ushort_t* z1lo  = (ushort_t*)(ws + 21725184);
  float*    z2    = ws + 23822336;                  //  8192x256 f32

  // 1. fused prep: cast + weight packing + s-zero in ONE launch
  prep_all<<<4512, 256, 0, stream>>>(x, xb, Wg, Wgp, W1, W1ph, W1pl,
                                     W2, W2ph, W2pl, s1);
  // 2. fused h-GEMM -> Bpack + s1/s2 (hbuf never materialized)
  gemm_h<<<dim3(4, 64, 2), 256, 0, stream>>>(xb, Wgp, a1, a2, Bpack, s1, s2);
  // 3. MFMA attention partials (R1 structure, verified local optimum)
  attn_mfma8<<<dim3(64, 4), 512, 0, stream>>>(Bpack, s1, s2, adj, pacc, pl);
  // 4. finalize -> embed emitted directly as hi/lo split (llm inline)
  attn_finalize<<<8192, 256, 0, stream>>>(pacc, pl, bg, llm, ehi, elo);
  // 5. z1 = LR(embed @ W1 + b1) -> hi/lo
  gemm_mlp<<<dim3(8, 64), 256, 0, stream>>>(
      ehi, elo, W1ph, W1pl, b1, nullptr, z1hi, z1lo, 8192, 512, 768, MLP_SLOPE);
  // 6. z2 = LR(z1 @ W2 + b2) -> fp32
  gemm_mlp<<<dim3(4, 64), 256, 0, stream>>>(
      z1hi, z1lo, W2ph, W2pl, b2, z2, nullptr, nullptr, 8192, 256, 512, MLP_SLOPE);
  // 7. edge dots
  pred_kernel<<<(E * 64 + 255) / 256, 256, 0, stream>>>(z2, ts, out, E);
}

// Round 9
// 573.416 us; speedup vs baseline: 1.1505x; 1.0045x over previous
//
#include <hip/hip_runtime.h>
#include <hip/hip_bf16.h>
#include <cstdint>
#include <cstddef>

#define ALPHA 0.2f
#define MLP_SLOPE 0.01f

typedef short bf16x8 __attribute__((ext_vector_type(8)));
typedef float f32x4 __attribute__((ext_vector_type(4)));
typedef unsigned short ushort_t;

// raw barrier: syncs LDS exchange WITHOUT draining vmcnt (global prefetches
// stay in flight across it).
#define ASM_BARRIER() __asm__ __volatile__("s_waitcnt lgkmcnt(0)\n\ts_barrier" ::: "memory")

__device__ __forceinline__ float lrelu(float x, float s) { return x > 0.f ? x : x * s; }
__device__ __forceinline__ ushort_t f2bf(float x) {
  __hip_bfloat16 h = __float2bfloat16(x);
  return *reinterpret_cast<ushort_t*>(&h);
}
__device__ __forceinline__ float bf2f(ushort_t u) {
  union { unsigned int i; float f; } v; v.i = ((unsigned int)u) << 16; return v.f;
}

// ---------------------------------------------------------------------------
// pack body: W[K,N] (batch offset b) into MFMA B-fragment order.
// ---------------------------------------------------------------------------
__device__ __forceinline__ void pack_body(
    const float* __restrict__ W, ushort_t* __restrict__ hi,
    ushort_t* __restrict__ lo, int K, int N, int gid, int batch)
{
  int lane = gid & 63;
  int kbc = K >> 5;
  int kblk = (gid >> 6) % kbc;
  int nblk = (gid >> 6) / kbc;
  size_t b = (size_t)batch * K * N;
  int col = nblk * 16 + (lane & 15);
  int krow = kblk * 32 + (lane >> 4) * 8;
  ushort_t h[8] __attribute__((aligned(16)));
  ushort_t l[8] __attribute__((aligned(16)));
#pragma unroll
  for (int e = 0; e < 8; ++e) {
    float v = W[b + (size_t)(krow + e) * N + col];
    h[e] = f2bf(v);
    l[e] = f2bf(v - bf2f(h[e]));
  }
  *(uint4*)&hi[b + (size_t)gid * 8] = *(uint4*)h;
  if (lo) *(uint4*)&lo[b + (size_t)gid * 8] = *(uint4*)l;
}

// ---------------------------------------------------------------------------
// prep_all: fuses tobf (4096 blocks) + pack Wg (128) + pack W1 (192) +
// pack W2 (64) + zero s1/s2 (32) into ONE launch = 4512 blocks. (R8 WIN)
// ---------------------------------------------------------------------------
__global__ __launch_bounds__(256) void prep_all(
    const float* __restrict__ x, ushort_t* __restrict__ xb,
    const float* __restrict__ Wg, ushort_t* __restrict__ Wgp,
    const float* __restrict__ W1, ushort_t* __restrict__ W1ph,
    ushort_t* __restrict__ W1pl,
    const float* __restrict__ W2, ushort_t* __restrict__ W2ph,
    ushort_t* __restrict__ W2pl, float* __restrict__ s12)
{
  const int b = blockIdx.x;
  const int t = threadIdx.x;
  if (b < 4096) {                       // tobf: x -> xb (bf16), 4 elems/thread
    int idx = b * 256 + t;
    float4 v = ((const float4*)x)[idx];
    ushort4 h;
    h.x = f2bf(v.x); h.y = f2bf(v.y); h.z = f2bf(v.z); h.w = f2bf(v.w);
    ((ushort4*)xb)[idx] = h;
  } else if (b < 4224) {                // pack Wg (2 heads x 64 blocks)
    int local = b - 4096;
    pack_body(Wg, Wgp, nullptr, 512, 256, (local & 63) * 256 + t, local >> 6);
  } else if (b < 4416) {                // pack W1 hi/lo
    int local = b - 4224;
    pack_body(W1, W1ph, W1pl, 768, 512, local * 256 + t, 0);
  } else if (b < 4480) {                // pack W2 hi/lo
    int local = b - 4416;
    pack_body(W2, W2ph, W2pl, 512, 256, local * 256 + t, 0);
  } else {                              // zero s1+s2 (contiguous 32768 floats)
    int idx = (b - 4480) * 256 + t;
    ((float4*)s12)[idx] = make_float4(0.f, 0.f, 0.f, 0.f);
  }
}

// ---------------------------------------------------------------------------
// Fused h-GEMM: h = x@Wg (single-pass bf16), epilogue writes Bpack (B-frag
// order) + atomic s1/s2 dots. h never materialized in fp32.  (R9, frozen)
// ---------------------------------------------------------------------------
__global__ __launch_bounds__(256, 2) void gemm_h(
    const ushort_t* __restrict__ xb, const ushort_t* __restrict__ Wgp,
    const float* __restrict__ a1, const float* __restrict__ a2,
    ushort_t* __restrict__ Bpack, float* __restrict__ s1,
    float* __restrict__ s2)
{
  __shared__ ushort_t Ab[2][128][40];
  const int t = threadIdx.x;
  const int head = blockIdx.z;
  const int m0 = blockIdx.y * 128;
  const int n0 = blockIdx.x * 64;
  const int wave = t >> 6;
  const int wm = (wave & 1) * 64, wn = (wave >> 1) * 32;
  const int l16 = t & 15, quad = (t >> 4) & 3, l63 = t & 63;
  const int sr = t >> 1, sp = (t & 1) * 16;
  const ushort_t* arow_g = xb + (size_t)(m0 + sr) * 512 + sp;
  const ushort_t* bp = Wgp + (size_t)head * 256 * 512;
  const int nb0 = (n0 + wn) >> 4;

  f32x4 acc[4][2];
#pragma unroll
  for (int i = 0; i < 4; ++i)
#pragma unroll
    for (int j = 0; j < 2; ++j) acc[i][j] = (f32x4){0.f, 0.f, 0.f, 0.f};

  uint4 r0, r1;
  r0 = *(const uint4*)(arow_g);
  r1 = *(const uint4*)(arow_g + 8);
  *(uint4*)&Ab[0][sr][sp] = r0;
  *(uint4*)&Ab[0][sr][sp + 8] = r1;
  __syncthreads();

  for (int kb = 0; kb < 16; ++kb) {
    const int cur = kb & 1, nxt = cur ^ 1;
    if (kb < 15) {
      const ushort_t* p = arow_g + (kb + 1) * 32;
      r0 = *(const uint4*)p;
      r1 = *(const uint4*)(p + 8);
    }
    bf16x8 Bf[2];
#pragma unroll
    for (int nt = 0; nt < 2; ++nt)
      Bf[nt] = *(const bf16x8*)&bp[(((size_t)(nb0 + nt) * 16 + kb) * 64 + l63) * 8];
    bf16x8 Af[4];
#pragma unroll
    for (int mt = 0; mt < 4; ++mt)
      Af[mt] = *(const bf16x8*)&Ab[cur][wm + mt * 16 + l16][quad * 8];
#pragma unroll
    for (int mt = 0; mt < 4; ++mt)
#pragma unroll
      for (int nt = 0; nt < 2; ++nt)
        acc[mt][nt] = __builtin_amdgcn_mfma_f32_16x16x32_bf16(
            Af[mt], Bf[nt], acc[mt][nt], 0, 0, 0);
    if (kb < 15) {
      *(uint4*)&Ab[nxt][sr][sp] = r0;
      *(uint4*)&Ab[nxt][sr][sp + 8] = r1;
    }
    __syncthreads();
  }

  // ---- epilogue 1: write Bpack in B-fragment order (bf16) ----
#pragma unroll
  for (int mt = 0; mt < 4; ++mt)
#pragma unroll
    for (int nt = 0; nt < 2; ++nt)
#pragma unroll
      for (int rg = 0; rg < 4; ++rg) {
        int j = m0 + wm + mt * 16 + quad * 4 + rg;
        int c = n0 + wn + nt * 16 + l16;
        int kblk = j >> 5;
        int laneb = ((j >> 3) & 3) * 16 + (c & 15);
        int e = j & 7;
        Bpack[(((size_t)head * 256 + kblk) * 16 + (c >> 4)) * 512 + laneb * 8 + e] =
            f2bf(acc[mt][nt][rg]);
      }
  // ---- epilogue 2: s1/s2 partial dots, shuffle-reduced over 16 cols ----
  float a1v[2], a2v[2];
#pragma unroll
  for (int nt = 0; nt < 2; ++nt) {
    int c = n0 + wn + nt * 16 + l16;
    a1v[nt] = a1[head * 256 + c];
    a2v[nt] = a2[head * 256 + c];
  }
#pragma unroll
  for (int mt = 0; mt < 4; ++mt)
#pragma unroll
    for (int rg = 0; rg < 4; ++rg) {
      float p1 = acc[mt][0][rg] * a1v[0] + acc[mt][1][rg] * a1v[1];
      float p2 = acc[mt][0][rg] * a2v[0] + acc[mt][1][rg] * a2v[1];
      p1 += __shfl_xor(p1, 1); p2 += __shfl_xor(p2, 1);
      p1 += __shfl_xor(p1, 2); p2 += __shfl_xor(p2, 2);
      p1 += __shfl_xor(p1, 4); p2 += __shfl_xor(p2, 4);
      p1 += __shfl_xor(p1, 8); p2 += __shfl_xor(p2, 8);
      if (l16 == 0) {
        int row = m0 + wm + mt * 16 + quad * 4 + rg;
        atomicAdd(&s1[head * 8192 + row], p1);
        atomicAdd(&s2[head * 8192 + row], p2);
      }
    }
}

// ---------------------------------------------------------------------------
// Pipelined split-bf16 MLP GEMM (R9, frozen).
// ---------------------------------------------------------------------------
__global__ __launch_bounds__(256, 2) void gemm_mlp(
    const ushort_t* __restrict__ Ahi, const ushort_t* __restrict__ Alo,
    const ushort_t* __restrict__ Bph, const ushort_t* __restrict__ Bpl,
    const float* __restrict__ bias, float* __restrict__ Cf,
    ushort_t* __restrict__ Chi, ushort_t* __restrict__ Clo,
    int M, int N, int K, float slope)
{
  __shared__ ushort_t Ah[2][128][40], Al[2][128][40];
  const int kbc = K >> 5;
  const int t = threadIdx.x;
  const int m0 = blockIdx.y * 128;
  const int n0 = blockIdx.x * 64;
  const int wave = t >> 6;
  const int wm = (wave & 1) * 64, wn = (wave >> 1) * 32;
  const int l16 = t & 15, quad = (t >> 4) & 3, l63 = t & 63;
  const int sr = t >> 1, sp = (t & 1) * 16;
  const ushort_t* ah_g = Ahi + (size_t)(m0 + sr) * K + sp;
  const ushort_t* al_g = Alo + (size_t)(m0 + sr) * K + sp;
  const int nb0 = (n0 + wn) >> 4;

  f32x4 acc[4][2];
#pragma unroll
  for (int i = 0; i < 4; ++i)
#pragma unroll
    for (int j = 0; j < 2; ++j) acc[i][j] = (f32x4){0.f, 0.f, 0.f, 0.f};

  uint4 rh0, rh1, rl0, rl1;
  rh0 = *(const uint4*)(ah_g);
  rh1 = *(const uint4*)(ah_g + 8);
  rl0 = *(const uint4*)(al_g);
  rl1 = *(const uint4*)(al_g + 8);
  *(uint4*)&Ah[0][sr][sp] = rh0;
  *(uint4*)&Ah[0][sr][sp + 8] = rh1;
  *(uint4*)&Al[0][sr][sp] = rl0;
  *(uint4*)&Al[0][sr][sp + 8] = rl1;
  __syncthreads();

  for (int kb = 0; kb < kbc; ++kb) {
    const int cur = kb & 1, nxt = cur ^ 1;
    if (kb + 1 < kbc) {
      const ushort_t* ph = ah_g + (kb + 1) * 32;
      const ushort_t* plo = al_g + (kb + 1) * 32;
      rh0 = *(const uint4*)ph;
      rh1 = *(const uint4*)(ph + 8);
      rl0 = *(const uint4*)plo;
      rl1 = *(const uint4*)(plo + 8);
    }
    bf16x8 bh[2], bl[2];
#pragma unroll
    for (int nt = 0; nt < 2; ++nt) {
      size_t o = (((size_t)(nb0 + nt) * kbc + kb) * 64 + l63) * 8;
      bh[nt] = *(const bf16x8*)&Bph[o];
      bl[nt] = *(const bf16x8*)&Bpl[o];
    }
    bf16x8 afh[4], afl[4];
#pragma unroll
    for (int mt = 0; mt < 4; ++mt) {
      afh[mt] = *(const bf16x8*)&Ah[cur][wm + mt * 16 + l16][quad * 8];
      afl[mt] = *(const bf16x8*)&Al[cur][wm + mt * 16 + l16][quad * 8];
    }
#pragma unroll
    for (int mt = 0; mt < 4; ++mt)
#pragma unroll
      for (int nt = 0; nt < 2; ++nt) {
        acc[mt][nt] = __builtin_amdgcn_mfma_f32_16x16x32_bf16(afh[mt], bh[nt], acc[mt][nt], 0, 0, 0);
        acc[mt][nt] = __builtin_amdgcn_mfma_f32_16x16x32_bf16(afh[mt], bl[nt], acc[mt][nt], 0, 0, 0);
        acc[mt][nt] = __builtin_amdgcn_mfma_f32_16x16x32_bf16(afl[mt], bh[nt], acc[mt][nt], 0, 0, 0);
      }
    if (kb + 1 < kbc) {
      *(uint4*)&Ah[nxt][sr][sp] = rh0;
      *(uint4*)&Ah[nxt][sr][sp + 8] = rh1;
      *(uint4*)&Al[nxt][sr][sp] = rl0;
      *(uint4*)&Al[nxt][sr][sp + 8] = rl1;
    }
    __syncthreads();
  }

#pragma unroll
  for (int mt = 0; mt < 4; ++mt)
#pragma unroll
    for (int nt = 0; nt < 2; ++nt)
#pragma unroll
      for (int rg = 0; rg < 4; ++rg) {
        int m = m0 + wm + mt * 16 + quad * 4 + rg;
        int n = n0 + wn + nt * 16 + l16;
        float v = lrelu(acc[mt][nt][rg] + bias[n], slope);
        size_t o = (size_t)m * N + n;
        if (Cf) Cf[o] = v;
        if (Chi) {
          ushort_t h = f2bf(v);
          Chi[o] = h; Clo[o] = f2bf(v - bf2f(h));
        }
      }
}

// ---------------------------------------------------------------------------
// MFMA attention v8 (R1, twice-verified): do not perturb (R3-R7 all failed).
// ---------------------------------------------------------------------------
__global__ __launch_bounds__(512, 1) void attn_mfma8(
    const ushort_t* __restrict__ Bpack, const float* __restrict__ s1g,
    const float* __restrict__ s2g, const int* __restrict__ adj,
    ushort_t* __restrict__ pacc, float* __restrict__ pl)
{
  __shared__ ushort_t Wlds[2][2][8][64][8];   // [buf][head][mt8][lane][8]
  const int t = threadIdx.x;
  const int i0 = blockIdx.x * 128;
  const int js = blockIdx.y;
  const int kbase = js * 2048;
  // generator mapping: row wr (0..127), k-octet kq (0..3)
  const int wr = t >> 2, kq = t & 3;
  const int glane = kq * 16 + (wr & 15);
  const int gmt = wr >> 4;                    // 0..7
  const float s1v0 = s1g[i0 + wr];
  const float s1v1 = s1g[8192 + i0 + wr];
  // consumer mapping: wave = (head, nh, rowgrp)
  const int wave = t >> 6;
  const int head = wave >> 2, nh = (wave >> 1) & 1, rg2 = wave & 1;
  const int l16 = t & 15, quad = (t >> 4) & 3;
  const int l63 = t & 63;
  f32x4 acc[4][8];
#pragma unroll
  for (int m = 0; m < 4; ++m)
#pragma unroll
    for (int n = 0; n < 8; ++n) acc[m][n] = (f32x4){0.f, 0.f, 0.f, 0.f};
  float rs0 = 0.f, rs1 = 0.f;

  const int* arow = adj + (size_t)(i0 + wr) * 8192;
  int4 pa0, pa1;
  float4 p20a, p20b, p21a, p21b;

  auto fetch = [&](int kk) {
    pa0 = *(const int4*)&arow[kk];
    pa1 = *(const int4*)&arow[kk + 4];
    p20a = *(const float4*)&s2g[kk];
    p20b = *(const float4*)&s2g[kk + 4];
    p21a = *(const float4*)&s2g[8192 + kk];
    p21b = *(const float4*)&s2g[8192 + kk + 4];
  };
  auto gen = [&](int buf) {
    int am[8] = {pa0.x, pa0.y, pa0.z, pa0.w, pa1.x, pa1.y, pa1.z, pa1.w};
    float s20[8] = {p20a.x, p20a.y, p20a.z, p20a.w, p20b.x, p20b.y, p20b.z, p20b.w};
    float s21[8] = {p21a.x, p21a.y, p21a.z, p21a.w, p21b.x, p21b.y, p21b.z, p21b.w};
    ushort_t w0[8] __attribute__((aligned(16)));
    ushort_t w1[8] __attribute__((aligned(16)));
#pragma unroll
    for (int e = 0; e < 8; ++e) {
      float e0 = s1v0 + s20[e];
      float e1 = s1v1 + s21[e];
      e0 = fmaxf(e0, 0.f) + ALPHA * fminf(e0, 0.f);
      e1 = fmaxf(e1, 0.f) + ALPHA * fminf(e1, 0.f);
      float v0 = am[e] > 0 ? __expf(e0) : 0.f;
      float v1 = am[e] > 0 ? __expf(e1) : 0.f;
      rs0 += v0; rs1 += v1;
      w0[e] = f2bf(v0); w1[e] = f2bf(v1);
    }
    *(uint4*)&Wlds[buf][0][gmt][glane][0] = *(uint4*)w0;
    *(uint4*)&Wlds[buf][1][gmt][glane][0] = *(uint4*)w1;
  };

  fetch(kbase + kq * 8);
  gen(0);
  fetch(kbase + 32 + kq * 8);
  ASM_BARRIER();

  for (int kt = 0; kt < 64; ++kt) {
    const int cur = kt & 1, nxt = cur ^ 1;
    const int kblk = js * 64 + kt;
    const ushort_t* bb =
        Bpack + ((((size_t)head * 256 + kblk) * 16 + nh * 8) * 64 + l63) * 8;
    bf16x8 Bf[8];
#pragma unroll
    for (int nt = 0; nt < 8; ++nt)
      Bf[nt] = *(const bf16x8*)&bb[nt * 512];
    bf16x8 Af[4];
#pragma unroll
    for (int mt = 0; mt < 4; ++mt)
      Af[mt] = *(const bf16x8*)&Wlds[cur][head][rg2 * 4 + mt][l63][0];
#pragma unroll
    for (int mt = 0; mt < 4; ++mt)
#pragma unroll
      for (int nt = 0; nt < 8; ++nt)
        acc[mt][nt] = __builtin_amdgcn_mfma_f32_16x16x32_bf16(
            Af[mt], Bf[nt], acc[mt][nt], 0, 0, 0);
    if (kt < 63) {
      gen(nxt);
      if (kt < 62) fetch(kbase + (kt + 2) * 32 + kq * 8);
    }
    ASM_BARRIER();
  }

  // denominators: reduce across the 4 kq lanes of each row
  rs0 += __shfl_xor(rs0, 1); rs0 += __shfl_xor(rs0, 2);
  rs1 += __shfl_xor(rs1, 1); rs1 += __shfl_xor(rs1, 2);
  if (kq == 0) {
    pl[((size_t)js * 2 + 0) * 8192 + i0 + wr] = rs0;
    pl[((size_t)js * 2 + 1) * 8192 + i0 + wr] = rs1;
  }
  // store bf16 partial numerators
  const int n0 = nh * 128;
#pragma unroll
  for (int mt = 0; mt < 4; ++mt)
#pragma unroll
    for (int nt = 0; nt < 8; ++nt)
#pragma unroll
      for (int rg = 0; rg < 4; ++rg) {
        int row = i0 + rg2 * 64 + mt * 16 + quad * 4 + rg;
        int col = n0 + nt * 16 + l16;
        pacc[(((size_t)js * 2 + head) * 8192 + row) * 256 + col] =
            f2bf(acc[mt][nt][rg]);
      }
}

// ---------------------------------------------------------------------------
// Finalize v2: vectorized per G13. 128 thr/block: llm via float4 (16B/lane),
// pacc via ushort2-in-uint (2 cols/thread, 4B/lane vs prior 2B scalar),
// bg via float2, tail writes ushort2. Same math per column; only the
// l2-norm reduction association changes (ulp-level).
// ---------------------------------------------------------------------------
__global__ __launch_bounds__(128) void attn_finalize(
    const ushort_t* __restrict__ pacc, const float* __restrict__ pl,
    const float* __restrict__ bg, const float* __restrict__ llm,
    ushort_t* __restrict__ ehi, ushort_t* __restrict__ elo)
{
  __shared__ float red[2][2];
  const int r = blockIdx.x;
  const int t = threadIdx.x;            // 0..127
  const int wv = t >> 6, lane = t & 63;

  // llm passthrough: 4 cols/thread, vectorized
  {
    float4 v = *(const float4*)&llm[(size_t)r * 512 + t * 4];
    ushort4 h, l;
    h.x = f2bf(v.x); l.x = f2bf(v.x - bf2f(h.x));
    h.y = f2bf(v.y); l.y = f2bf(v.y - bf2f(h.y));
    h.z = f2bf(v.z); l.z = f2bf(v.z - bf2f(h.z));
    h.w = f2bf(v.w); l.w = f2bf(v.w - bf2f(h.w));
    *(ushort4*)&ehi[(size_t)r * 768 + t * 4] = h;
    *(ushort4*)&elo[(size_t)r * 768 + t * 4] = l;
  }
  // gnn part: 2 cols/thread
  const int c0 = t * 2;
  float o[2][2];
#pragma unroll
  for (int hh = 0; hh < 2; ++hh) {
    float n0 = 0.f, n1 = 0.f, l = 0.f;
#pragma unroll
    for (int js = 0; js < 4; ++js) {
      unsigned int u =
          *(const unsigned int*)&pacc[(((size_t)js * 2 + hh) * 8192 + r) * 256 + c0];
      n0 += bf2f((ushort_t)(u & 0xffffu));
      n1 += bf2f((ushort_t)(u >> 16));
      l += pl[((size_t)js * 2 + hh) * 8192 + r];
    }
    o[hh][0] = lrelu(n0 / l, ALPHA);
    o[hh][1] = lrelu(n1 / l, ALPHA);
  }
  float v0 = o[0][0] * o[0][0] + o[0][1] * o[0][1];
  float v1 = o[1][0] * o[1][0] + o[1][1] * o[1][1];
  for (int off = 32; off > 0; off >>= 1) {
    v0 += __shfl_xor(v0, off);
    v1 += __shfl_xor(v1, off);
  }
  if (lane == 0) { red[wv][0] = v0; red[wv][1] = v1; }
  __syncthreads();
  float nn0 = fmaxf(sqrtf(red[0][0] + red[1][0]), 1e-12f);
  float nn1 = fmaxf(sqrtf(red[0][1] + red[1][1]), 1e-12f);
  float2 bg0 = *(const float2*)&bg[c0];
  float2 bg1 = *(const float2*)&bg[256 + c0];
  float val0 = 0.5f * (o[0][0] / nn0 + bg0.x + o[1][0] / nn1 + bg1.x);
  float val1 = 0.5f * (o[0][1] / nn0 + bg0.y + o[1][1] / nn1 + bg1.y);
  ushort_t h0 = f2bf(val0), h1 = f2bf(val1);
  ushort2 hv; hv.x = h0; hv.y = h1;
  ushort2 lv; lv.x = f2bf(val0 - bf2f(h0)); lv.y = f2bf(val1 - bf2f(h1));
  *(ushort2*)&ehi[(size_t)r * 768 + 512 + c0] = hv;
  *(ushort2*)&elo[(size_t)r * 768 + 512 + c0] = lv;
}

// ---------------------------------------------------------------------------
__global__ __launch_bounds__(256) void pred_kernel(
    const float* __restrict__ z2, const int* __restrict__ ts,
    float* __restrict__ out, int E)
{
  const int gw = (blockIdx.x * 256 + threadIdx.x) >> 6;
  const int lane = threadIdx.x & 63;
  if (gw >= E) return;
  const int a = ts[gw * 2], b = ts[gw * 2 + 1];
  float4 va = ((const float4*)(z2 + (size_t)a * 256))[lane];
  float4 vb = ((const float4*)(z2 + (size_t)b * 256))[lane];
  float p = va.x * vb.x + va.y * vb.y + va.z * vb.z + va.w * vb.w;
  for (int off = 32; off > 0; off >>= 1) p += __shfl_xor(p, off);
  if (lane == 0) out[gw] = p;
}

// ---------------------------------------------------------------------------
extern "C" void kernel_launch(void* const* d_in, const int* in_sizes, int n_in,
                              void* d_out, int out_size, void* d_ws, size_t ws_size,
                              hipStream_t stream) {
  const float* x   = (const float*)d_in[0];
  const int*   adj = (const int*)d_in[1];
  const int*   ts  = (const int*)d_in[2];
  const float* llm = (const float*)d_in[3];
  const float* Wg  = (const float*)d_in[4];
  const float* a1  = (const float*)d_in[5];
  const float* a2  = (const float*)d_in[6];
  const float* bg  = (const float*)d_in[7];
  const float* W1  = (const float*)d_in[8];
  const float* b1  = (const float*)d_in[9];
  const float* W2  = (const float*)d_in[10];
  const float* b2  = (const float*)d_in[11];
  float* out = (float*)d_out;
  float* ws  = (float*)d_ws;
  const int E = in_sizes[2] / 2;

  // ---- workspace layout (float words) ----
  ushort_t* xb    = (ushort_t*)(ws + 0);            //  8192x512 bf16
  ushort_t* Wgp   = (ushort_t*)(ws + 2097152);      //  2x512x256
  ushort_t* W1ph  = (ushort_t*)(ws + 2228224);      //  768x512
  ushort_t* W1pl  = (ushort_t*)(ws + 2424832);
  ushort_t* W2ph  = (ushort_t*)(ws + 2621440);      //  512x256
  ushort_t* W2pl  = (ushort_t*)(ws + 2686976);
  ushort_t* Bpack = (ushort_t*)(ws + 2752512);      //  2x8192x256
  float*    s1    = ws + 4849664;                   //  2x8192
  float*    s2    = ws + 4866048;
  float*    pl    = ws + 4882432;                   //  8x8192
  ushort_t* pacc  = (ushort_t*)(ws + 4947968);      //  8x8192x256
  ushort_t* ehi   = (ushort_t*)(ws + 13336576);     //  8192x768
  ushort_t* elo   = (ushort_t*)(ws + 16482304);
  ushort_t* z1hi  = (ushort_t*)(ws + 19628032);     //  8192x512
  ushort_t* z1lo  = (ushort_t*)(ws + 21725184);
  float*    z2    = ws + 23822336;                  //  8192x256 f32

  // 1. fused prep: cast + weight packing + s-zero in ONE launch
  prep_all<<<4512, 256, 0, stream>>>(x, xb, Wg, Wgp, W1, W1ph, W1pl,
                                     W2, W2ph, W2pl, s1);
  // 2. fused h-GEMM -> Bpack + s1/s2 (hbuf never materialized)
  gemm_h<<<dim3(4, 64, 2), 256, 0, stream>>>(xb, Wgp, a1, a2, Bpack, s1, s2);
  // 3. MFMA attention partials (R1 structure, verified local optimum)
  attn_mfma8<<<dim3(64, 4), 512, 0, stream>>>(Bpack, s1, s2, adj, pacc, pl);
  // 4. finalize -> embed emitted directly as hi/lo split (vectorized, G13)
  attn_finalize<<<8192, 128, 0, stream>>>(pacc, pl, bg, llm, ehi, elo);
  // 5. z1 = LR(embed @ W1 + b1) -> hi/lo
  gemm_mlp<<<dim3(8, 64), 256, 0, stream>>>(
      ehi, elo, W1ph, W1pl, b1, nullptr, z1hi, z1lo, 8192, 512, 768, MLP_SLOPE);
  // 6. z2 = LR(z1 @ W2 + b2) -> fp32
  gemm_mlp<<<dim3(4, 64), 256, 0, stream>>>(
      z1hi, z1lo, W2ph, W2pl, b2, z2, nullptr, nullptr, 8192, 256, 512, MLP_SLOPE);
  // 7. edge dots
  pred_kernel<<<(E * 64 + 255) / 256, 256, 0, stream>>>(z2, ts, out, E);
}

// Round 10
// 557.892 us; speedup vs baseline: 1.1825x; 1.0278x over previous
//
#include <hip/hip_runtime.h>
#include <hip/hip_bf16.h>
#include <cstdint>
#include <cstddef>

#define ALPHA 0.2f
#define MLP_SLOPE 0.01f

typedef short bf16x8 __attribute__((ext_vector_type(8)));
typedef float f32x4 __attribute__((ext_vector_type(4)));
typedef unsigned short ushort_t;

// raw barrier: syncs LDS exchange WITHOUT draining vmcnt (global prefetches
// stay in flight across it).
#define ASM_BARRIER() __asm__ __volatile__("s_waitcnt lgkmcnt(0)\n\ts_barrier" ::: "memory")

__device__ __forceinline__ float lrelu(float x, float s) { return x > 0.f ? x : x * s; }
__device__ __forceinline__ ushort_t f2bf(float x) {
  __hip_bfloat16 h = __float2bfloat16(x);
  return *reinterpret_cast<ushort_t*>(&h);
}
__device__ __forceinline__ float bf2f(ushort_t u) {
  union { unsigned int i; float f; } v; v.i = ((unsigned int)u) << 16; return v.f;
}

// ---------------------------------------------------------------------------
// pack body: W[K,N] (batch offset b) into MFMA B-fragment order.
// ---------------------------------------------------------------------------
__device__ __forceinline__ void pack_body(
    const float* __restrict__ W, ushort_t* __restrict__ hi,
    ushort_t* __restrict__ lo, int K, int N, int gid, int batch)
{
  int lane = gid & 63;
  int kbc = K >> 5;
  int kblk = (gid >> 6) % kbc;
  int nblk = (gid >> 6) / kbc;
  size_t b = (size_t)batch * K * N;
  int col = nblk * 16 + (lane & 15);
  int krow = kblk * 32 + (lane >> 4) * 8;
  ushort_t h[8] __attribute__((aligned(16)));
  ushort_t l[8] __attribute__((aligned(16)));
#pragma unroll
  for (int e = 0; e < 8; ++e) {
    float v = W[b + (size_t)(krow + e) * N + col];
    h[e] = f2bf(v);
    l[e] = f2bf(v - bf2f(h[e]));
  }
  *(uint4*)&hi[b + (size_t)gid * 8] = *(uint4*)h;
  if (lo) *(uint4*)&lo[b + (size_t)gid * 8] = *(uint4*)l;
}

// ---------------------------------------------------------------------------
// prep_all: fuses tobf (4096 blocks) + pack Wg (128) + pack W1 (192) +
// pack W2 (64) + zero s1/s2 (32) into ONE launch = 4512 blocks. (R8 WIN)
// ---------------------------------------------------------------------------
__global__ __launch_bounds__(256) void prep_all(
    const float* __restrict__ x, ushort_t* __restrict__ xb,
    const float* __restrict__ Wg, ushort_t* __restrict__ Wgp,
    const float* __restrict__ W1, ushort_t* __restrict__ W1ph,
    ushort_t* __restrict__ W1pl,
    const float* __restrict__ W2, ushort_t* __restrict__ W2ph,
    ushort_t* __restrict__ W2pl, float* __restrict__ s12)
{
  const int b = blockIdx.x;
  const int t = threadIdx.x;
  if (b < 4096) {                       // tobf: x -> xb (bf16), 4 elems/thread
    int idx = b * 256 + t;
    float4 v = ((const float4*)x)[idx];
    ushort4 h;
    h.x = f2bf(v.x); h.y = f2bf(v.y); h.z = f2bf(v.z); h.w = f2bf(v.w);
    ((ushort4*)xb)[idx] = h;
  } else if (b < 4224) {                // pack Wg (2 heads x 64 blocks)
    int local = b - 4096;
    pack_body(Wg, Wgp, nullptr, 512, 256, (local & 63) * 256 + t, local >> 6);
  } else if (b < 4416) {                // pack W1 hi/lo
    int local = b - 4224;
    pack_body(W1, W1ph, W1pl, 768, 512, local * 256 + t, 0);
  } else if (b < 4480) {                // pack W2 hi/lo
    int local = b - 4416;
    pack_body(W2, W2ph, W2pl, 512, 256, local * 256 + t, 0);
  } else {                              // zero s1+s2 (contiguous 32768 floats)
    int idx = (b - 4480) * 256 + t;
    ((float4*)s12)[idx] = make_float4(0.f, 0.f, 0.f, 0.f);
  }
}

// ---------------------------------------------------------------------------
// Fused h-GEMM (R10: XCD-aware block decode). All 8 blocks sharing an
// A-panel (4 n-blocks x 2 heads) satisfy lid%8 == m%8 -> same XCD L2,
// n/head fastest-varying -> panel fetched once per XCD instead of 8x HBM.
// Math identical; only block->work mapping changes.
// ---------------------------------------------------------------------------
__global__ __launch_bounds__(256, 2) void gemm_h(
    const ushort_t* __restrict__ xb, const ushort_t* __restrict__ Wgp,
    const float* __restrict__ a1, const float* __restrict__ a2,
    ushort_t* __restrict__ Bpack, float* __restrict__ s1,
    float* __restrict__ s2)
{
  __shared__ ushort_t Ab[2][128][40];
  const int t = threadIdx.x;
  // XCD-aware decode: lid in [0,512). xcd=lid&7 pins m%8; (n,head) fastest.
  const int lid = (blockIdx.z * gridDim.y + blockIdx.y) * gridDim.x + blockIdx.x;
  const int xcd = lid & 7;
  const int rest = lid >> 3;            // 0..63
  const int nh = rest & 7;              // n + 4*head
  const int head = nh >> 2;
  const int m0 = (xcd + 8 * (rest >> 3)) * 128;
  const int n0 = (nh & 3) * 64;
  const int wave = t >> 6;
  const int wm = (wave & 1) * 64, wn = (wave >> 1) * 32;
  const int l16 = t & 15, quad = (t >> 4) & 3, l63 = t & 63;
  const int sr = t >> 1, sp = (t & 1) * 16;
  const ushort_t* arow_g = xb + (size_t)(m0 + sr) * 512 + sp;
  const ushort_t* bp = Wgp + (size_t)head * 256 * 512;
  const int nb0 = (n0 + wn) >> 4;

  f32x4 acc[4][2];
#pragma unroll
  for (int i = 0; i < 4; ++i)
#pragma unroll
    for (int j = 0; j < 2; ++j) acc[i][j] = (f32x4){0.f, 0.f, 0.f, 0.f};

  uint4 r0, r1;
  r0 = *(const uint4*)(arow_g);
  r1 = *(const uint4*)(arow_g + 8);
  *(uint4*)&Ab[0][sr][sp] = r0;
  *(uint4*)&Ab[0][sr][sp + 8] = r1;
  __syncthreads();

  for (int kb = 0; kb < 16; ++kb) {
    const int cur = kb & 1, nxt = cur ^ 1;
    if (kb < 15) {
      const ushort_t* p = arow_g + (kb + 1) * 32;
      r0 = *(const uint4*)p;
      r1 = *(const uint4*)(p + 8);
    }
    bf16x8 Bf[2];
#pragma unroll
    for (int nt = 0; nt < 2; ++nt)
      Bf[nt] = *(const bf16x8*)&bp[(((size_t)(nb0 + nt) * 16 + kb) * 64 + l63) * 8];
    bf16x8 Af[4];
#pragma unroll
    for (int mt = 0; mt < 4; ++mt)
      Af[mt] = *(const bf16x8*)&Ab[cur][wm + mt * 16 + l16][quad * 8];
#pragma unroll
    for (int mt = 0; mt < 4; ++mt)
#pragma unroll
      for (int nt = 0; nt < 2; ++nt)
        acc[mt][nt] = __builtin_amdgcn_mfma_f32_16x16x32_bf16(
            Af[mt], Bf[nt], acc[mt][nt], 0, 0, 0);
    if (kb < 15) {
      *(uint4*)&Ab[nxt][sr][sp] = r0;
      *(uint4*)&Ab[nxt][sr][sp + 8] = r1;
    }
    __syncthreads();
  }

  // ---- epilogue 1: write Bpack in B-fragment order (bf16) ----
#pragma unroll
  for (int mt = 0; mt < 4; ++mt)
#pragma unroll
    for (int nt = 0; nt < 2; ++nt)
#pragma unroll
      for (int rg = 0; rg < 4; ++rg) {
        int j = m0 + wm + mt * 16 + quad * 4 + rg;
        int c = n0 + wn + nt * 16 + l16;
        int kblk = j >> 5;
        int laneb = ((j >> 3) & 3) * 16 + (c & 15);
        int e = j & 7;
        Bpack[(((size_t)head * 256 + kblk) * 16 + (c >> 4)) * 512 + laneb * 8 + e] =
            f2bf(acc[mt][nt][rg]);
      }
  // ---- epilogue 2: s1/s2 partial dots, shuffle-reduced over 16 cols ----
  float a1v[2], a2v[2];
#pragma unroll
  for (int nt = 0; nt < 2; ++nt) {
    int c = n0 + wn + nt * 16 + l16;
    a1v[nt] = a1[head * 256 + c];
    a2v[nt] = a2[head * 256 + c];
  }
#pragma unroll
  for (int mt = 0; mt < 4; ++mt)
#pragma unroll
    for (int rg = 0; rg < 4; ++rg) {
      float p1 = acc[mt][0][rg] * a1v[0] + acc[mt][1][rg] * a1v[1];
      float p2 = acc[mt][0][rg] * a2v[0] + acc[mt][1][rg] * a2v[1];
      p1 += __shfl_xor(p1, 1); p2 += __shfl_xor(p2, 1);
      p1 += __shfl_xor(p1, 2); p2 += __shfl_xor(p2, 2);
      p1 += __shfl_xor(p1, 4); p2 += __shfl_xor(p2, 4);
      p1 += __shfl_xor(p1, 8); p2 += __shfl_xor(p2, 8);
      if (l16 == 0) {
        int row = m0 + wm + mt * 16 + quad * 4 + rg;
        atomicAdd(&s1[head * 8192 + row], p1);
        atomicAdd(&s2[head * 8192 + row], p2);
      }
    }
}

// ---------------------------------------------------------------------------
// Pipelined split-bf16 MLP GEMM (R10: XCD-aware block decode -- all n-blocks
// of one A-panel land on the same XCD, n fastest -> A fetched ~once per XCD
// L2 instead of nx times from HBM). Math identical.
// ---------------------------------------------------------------------------
__global__ __launch_bounds__(256, 2) void gemm_mlp(
    const ushort_t* __restrict__ Ahi, const ushort_t* __restrict__ Alo,
    const ushort_t* __restrict__ Bph, const ushort_t* __restrict__ Bpl,
    const float* __restrict__ bias, float* __restrict__ Cf,
    ushort_t* __restrict__ Chi, ushort_t* __restrict__ Clo,
    int M, int N, int K, float slope)
{
  __shared__ ushort_t Ah[2][128][40], Al[2][128][40];
  const int kbc = K >> 5;
  const int t = threadIdx.x;
  // XCD-aware decode: nwg = nx*64 (divisible by 8); xcd pins m%8.
  const int nx = gridDim.x;
  const int lid = blockIdx.y * nx + blockIdx.x;
  const int xcd = lid & 7;
  const int rest = lid >> 3;
  const int m0 = (xcd + 8 * (rest / nx)) * 128;
  const int n0 = (rest % nx) * 64;
  const int wave = t >> 6;
  const int wm = (wave & 1) * 64, wn = (wave >> 1) * 32;
  const int l16 = t & 15, quad = (t >> 4) & 3, l63 = t & 63;
  const int sr = t >> 1, sp = (t & 1) * 16;
  const ushort_t* ah_g = Ahi + (size_t)(m0 + sr) * K + sp;
  const ushort_t* al_g = Alo + (size_t)(m0 + sr) * K + sp;
  const int nb0 = (n0 + wn) >> 4;

  f32x4 acc[4][2];
#pragma unroll
  for (int i = 0; i < 4; ++i)
#pragma unroll
    for (int j = 0; j < 2; ++j) acc[i][j] = (f32x4){0.f, 0.f, 0.f, 0.f};

  uint4 rh0, rh1, rl0, rl1;
  rh0 = *(const uint4*)(ah_g);
  rh1 = *(const uint4*)(ah_g + 8);
  rl0 = *(const uint4*)(al_g);
  rl1 = *(const uint4*)(al_g + 8);
  *(uint4*)&Ah[0][sr][sp] = rh0;
  *(uint4*)&Ah[0][sr][sp + 8] = rh1;
  *(uint4*)&Al[0][sr][sp] = rl0;
  *(uint4*)&Al[0][sr][sp + 8] = rl1;
  __syncthreads();

  for (int kb = 0; kb < kbc; ++kb) {
    const int cur = kb & 1, nxt = cur ^ 1;
    if (kb + 1 < kbc) {
      const ushort_t* ph = ah_g + (kb + 1) * 32;
      const ushort_t* plo = al_g + (kb + 1) * 32;
      rh0 = *(const uint4*)ph;
      rh1 = *(const uint4*)(ph + 8);
      rl0 = *(const uint4*)plo;
      rl1 = *(const uint4*)(plo + 8);
    }
    bf16x8 bh[2], bl[2];
#pragma unroll
    for (int nt = 0; nt < 2; ++nt) {
      size_t o = (((size_t)(nb0 + nt) * kbc + kb) * 64 + l63) * 8;
      bh[nt] = *(const bf16x8*)&Bph[o];
      bl[nt] = *(const bf16x8*)&Bpl[o];
    }
    bf16x8 afh[4], afl[4];
#pragma unroll
    for (int mt = 0; mt < 4; ++mt) {
      afh[mt] = *(const bf16x8*)&Ah[cur][wm + mt * 16 + l16][quad * 8];
      afl[mt] = *(const bf16x8*)&Al[cur][wm + mt * 16 + l16][quad * 8];
    }
#pragma unroll
    for (int mt = 0; mt < 4; ++mt)
#pragma unroll
      for (int nt = 0; nt < 2; ++nt) {
        acc[mt][nt] = __builtin_amdgcn_mfma_f32_16x16x32_bf16(afh[mt], bh[nt], acc[mt][nt], 0, 0, 0);
        acc[mt][nt] = __builtin_amdgcn_mfma_f32_16x16x32_bf16(afh[mt], bl[nt], acc[mt][nt], 0, 0, 0);
        acc[mt][nt] = __builtin_amdgcn_mfma_f32_16x16x32_bf16(afl[mt], bh[nt], acc[mt][nt], 0, 0, 0);
      }
    if (kb + 1 < kbc) {
      *(uint4*)&Ah[nxt][sr][sp] = rh0;
      *(uint4*)&Ah[nxt][sr][sp + 8] = rh1;
      *(uint4*)&Al[nxt][sr][sp] = rl0;
      *(uint4*)&Al[nxt][sr][sp + 8] = rl1;
    }
    __syncthreads();
  }

#pragma unroll
  for (int mt = 0; mt < 4; ++mt)
#pragma unroll
    for (int nt = 0; nt < 2; ++nt)
#pragma unroll
      for (int rg = 0; rg < 4; ++rg) {
        int m = m0 + wm + mt * 16 + quad * 4 + rg;
        int n = n0 + wn + nt * 16 + l16;
        float v = lrelu(acc[mt][nt][rg] + bias[n], slope);
        size_t o = (size_t)m * N + n;
        if (Cf) Cf[o] = v;
        if (Chi) {
          ushort_t h = f2bf(v);
          Chi[o] = h; Clo[o] = f2bf(v - bf2f(h));
        }
      }
}

// ---------------------------------------------------------------------------
// MFMA attention v8 (R1, twice-verified): do not perturb (R3-R7 all failed).
// ---------------------------------------------------------------------------
__global__ __launch_bounds__(512, 1) void attn_mfma8(
    const ushort_t* __restrict__ Bpack, const float* __restrict__ s1g,
    const float* __restrict__ s2g, const int* __restrict__ adj,
    ushort_t* __restrict__ pacc, float* __restrict__ pl)
{
  __shared__ ushort_t Wlds[2][2][8][64][8];   // [buf][head][mt8][lane][8]
  const int t = threadIdx.x;
  const int i0 = blockIdx.x * 128;
  const int js = blockIdx.y;
  const int kbase = js * 2048;
  // generator mapping: row wr (0..127), k-octet kq (0..3)
  const int wr = t >> 2, kq = t & 3;
  const int glane = kq * 16 + (wr & 15);
  const int gmt = wr >> 4;                    // 0..7
  const float s1v0 = s1g[i0 + wr];
  const float s1v1 = s1g[8192 + i0 + wr];
  // consumer mapping: wave = (head, nh, rowgrp)
  const int wave = t >> 6;
  const int head = wave >> 2, nh = (wave >> 1) & 1, rg2 = wave & 1;
  const int l16 = t & 15, quad = (t >> 4) & 3;
  const int l63 = t & 63;
  f32x4 acc[4][8];
#pragma unroll
  for (int m = 0; m < 4; ++m)
#pragma unroll
    for (int n = 0; n < 8; ++n) acc[m][n] = (f32x4){0.f, 0.f, 0.f, 0.f};
  float rs0 = 0.f, rs1 = 0.f;

  const int* arow = adj + (size_t)(i0 + wr) * 8192;
  int4 pa0, pa1;
  float4 p20a, p20b, p21a, p21b;

  auto fetch = [&](int kk) {
    pa0 = *(const int4*)&arow[kk];
    pa1 = *(const int4*)&arow[kk + 4];
    p20a = *(const float4*)&s2g[kk];
    p20b = *(const float4*)&s2g[kk + 4];
    p21a = *(const float4*)&s2g[8192 + kk];
    p21b = *(const float4*)&s2g[8192 + kk + 4];
  };
  auto gen = [&](int buf) {
    int am[8] = {pa0.x, pa0.y, pa0.z, pa0.w, pa1.x, pa1.y, pa1.z, pa1.w};
    float s20[8] = {p20a.x, p20a.y, p20a.z, p20a.w, p20b.x, p20b.y, p20b.z, p20b.w};
    float s21[8] = {p21a.x, p21a.y, p21a.z, p21a.w, p21b.x, p21b.y, p21b.z, p21b.w};
    ushort_t w0[8] __attribute__((aligned(16)));
    ushort_t w1[8] __attribute__((aligned(16)));
#pragma unroll
    for (int e = 0; e < 8; ++e) {
      float e0 = s1v0 + s20[e];
      float e1 = s1v1 + s21[e];
      e0 = fmaxf(e0, 0.f) + ALPHA * fminf(e0, 0.f);
      e1 = fmaxf(e1, 0.f) + ALPHA * fminf(e1, 0.f);
      float v0 = am[e] > 0 ? __expf(e0) : 0.f;
      float v1 = am[e] > 0 ? __expf(e1) : 0.f;
      rs0 += v0; rs1 += v1;
      w0[e] = f2bf(v0); w1[e] = f2bf(v1);
    }
    *(uint4*)&Wlds[buf][0][gmt][glane][0] = *(uint4*)w0;
    *(uint4*)&Wlds[buf][1][gmt][glane][0] = *(uint4*)w1;
  };

  fetch(kbase + kq * 8);
  gen(0);
  fetch(kbase + 32 + kq * 8);
  ASM_BARRIER();

  for (int kt = 0; kt < 64; ++kt) {
    const int cur = kt & 1, nxt = cur ^ 1;
    const int kblk = js * 64 + kt;
    const ushort_t* bb =
        Bpack + ((((size_t)head * 256 + kblk) * 16 + nh * 8) * 64 + l63) * 8;
    bf16x8 Bf[8];
#pragma unroll
    for (int nt = 0; nt < 8; ++nt)
      Bf[nt] = *(const bf16x8*)&bb[nt * 512];
    bf16x8 Af[4];
#pragma unroll
    for (int mt = 0; mt < 4; ++mt)
      Af[mt] = *(const bf16x8*)&Wlds[cur][head][rg2 * 4 + mt][l63][0];
#pragma unroll
    for (int mt = 0; mt < 4; ++mt)
#pragma unroll
      for (int nt = 0; nt < 8; ++nt)
        acc[mt][nt] = __builtin_amdgcn_mfma_f32_16x16x32_bf16(
            Af[mt], Bf[nt], acc[mt][nt], 0, 0, 0);
    if (kt < 63) {
      gen(nxt);
      if (kt < 62) fetch(kbase + (kt + 2) * 32 + kq * 8);
    }
    ASM_BARRIER();
  }

  // denominators: reduce across the 4 kq lanes of each row
  rs0 += __shfl_xor(rs0, 1); rs0 += __shfl_xor(rs0, 2);
  rs1 += __shfl_xor(rs1, 1); rs1 += __shfl_xor(rs1, 2);
  if (kq == 0) {
    pl[((size_t)js * 2 + 0) * 8192 + i0 + wr] = rs0;
    pl[((size_t)js * 2 + 1) * 8192 + i0 + wr] = rs1;
  }
  // store bf16 partial numerators
  const int n0 = nh * 128;
#pragma unroll
  for (int mt = 0; mt < 4; ++mt)
#pragma unroll
    for (int nt = 0; nt < 8; ++nt)
#pragma unroll
      for (int rg = 0; rg < 4; ++rg) {
        int row = i0 + rg2 * 64 + mt * 16 + quad * 4 + rg;
        int col = n0 + nt * 16 + l16;
        pacc[(((size_t)js * 2 + head) * 8192 + row) * 256 + col] =
            f2bf(acc[mt][nt][rg]);
      }
}

// ---------------------------------------------------------------------------
// Finalize v2 (R9 WIN): vectorized per G13. 128 thr/block.
// ---------------------------------------------------------------------------
__global__ __launch_bounds__(128) void attn_finalize(
    const ushort_t* __restrict__ pacc, const float* __restrict__ pl,
    const float* __restrict__ bg, const float* __restrict__ llm,
    ushort_t* __restrict__ ehi, ushort_t* __restrict__ elo)
{
  __shared__ float red[2][2];
  const int r = blockIdx.x;
  const int t = threadIdx.x;            // 0..127
  const int wv = t >> 6, lane = t & 63;

  // llm passthrough: 4 cols/thread, vectorized
  {
    float4 v = *(const float4*)&llm[(size_t)r * 512 + t * 4];
    ushort4 h, l;
    h.x = f2bf(v.x); l.x = f2bf(v.x - bf2f(h.x));
    h.y = f2bf(v.y); l.y = f2bf(v.y - bf2f(h.y));
    h.z = f2bf(v.z); l.z = f2bf(v.z - bf2f(h.z));
    h.w = f2bf(v.w); l.w = f2bf(v.w - bf2f(h.w));
    *(ushort4*)&ehi[(size_t)r * 768 + t * 4] = h;
    *(ushort4*)&elo[(size_t)r * 768 + t * 4] = l;
  }
  // gnn part: 2 cols/thread
  const int c0 = t * 2;
  float o[2][2];
#pragma unroll
  for (int hh = 0; hh < 2; ++hh) {
    float n0 = 0.f, n1 = 0.f, l = 0.f;
#pragma unroll
    for (int js = 0; js < 4; ++js) {
      unsigned int u =
          *(const unsigned int*)&pacc[(((size_t)js * 2 + hh) * 8192 + r) * 256 + c0];
      n0 += bf2f((ushort_t)(u & 0xffffu));
      n1 += bf2f((ushort_t)(u >> 16));
      l += pl[((size_t)js * 2 + hh) * 8192 + r];
    }
    o[hh][0] = lrelu(n0 / l, ALPHA);
    o[hh][1] = lrelu(n1 / l, ALPHA);
  }
  float v0 = o[0][0] * o[0][0] + o[0][1] * o[0][1];
  float v1 = o[1][0] * o[1][0] + o[1][1] * o[1][1];
  for (int off = 32; off > 0; off >>= 1) {
    v0 += __shfl_xor(v0, off);
    v1 += __shfl_xor(v1, off);
  }
  if (lane == 0) { red[wv][0] = v0; red[wv][1] = v1; }
  __syncthreads();
  float nn0 = fmaxf(sqrtf(red[0][0] + red[1][0]), 1e-12f);
  float nn1 = fmaxf(sqrtf(red[0][1] + red[1][1]), 1e-12f);
  float2 bg0 = *(const float2*)&bg[c0];
  float2 bg1 = *(const float2*)&bg[256 + c0];
  float val0 = 0.5f * (o[0][0] / nn0 + bg0.x + o[1][0] / nn1 + bg1.x);
  float val1 = 0.5f * (o[0][1] / nn0 + bg0.y + o[1][1] / nn1 + bg1.y);
  ushort_t h0 = f2bf(val0), h1 = f2bf(val1);
  ushort2 hv; hv.x = h0; hv.y = h1;
  ushort2 lv; lv.x = f2bf(val0 - bf2f(h0)); lv.y = f2bf(val1 - bf2f(h1));
  *(ushort2*)&ehi[(size_t)r * 768 + 512 + c0] = hv;
  *(ushort2*)&elo[(size_t)r * 768 + 512 + c0] = lv;
}

// ---------------------------------------------------------------------------
__global__ __launch_bounds__(256) void pred_kernel(
    const float* __restrict__ z2, const int* __restrict__ ts,
    float* __restrict__ out, int E)
{
  const int gw = (blockIdx.x * 256 + threadIdx.x) >> 6;
  const int lane = threadIdx.x & 63;
  if (gw >= E) return;
  const int a = ts[gw * 2], b = ts[gw * 2 + 1];
  float4 va = ((const float4*)(z2 + (size_t)a * 256))[lane];
  float4 vb = ((const float4*)(z2 + (size_t)b * 256))[lane];
  float p = va.x * vb.x + va.y * vb.y + va.z * vb.z + va.w * vb.w;
  for (int off = 32; off > 0; off >>= 1) p += __shfl_xor(p, off);
  if (lane == 0) out[gw] = p;
}

// ---------------------------------------------------------------------------
extern "C" void kernel_launch(void* const* d_in, const int* in_sizes, int n_in,
                              void* d_out, int out_size, void* d_ws, size_t ws_size,
                              hipStream_t stream) {
  const float* x   = (const float*)d_in[0];
  const int*   adj = (const int*)d_in[1];
  const int*   ts  = (const int*)d_in[2];
  const float* llm = (const float*)d_in[3];
  const float* Wg  = (const float*)d_in[4];
  const float* a1  = (const float*)d_in[5];
  const float* a2  = (const float*)d_in[6];
  const float* bg  = (const float*)d_in[7];
  const float* W1  = (const float*)d_in[8];
  const float* b1  = (const float*)d_in[9];
  const float* W2  = (const float*)d_in[10];
  const float* b2  = (const float*)d_in[11];
  float* out = (float*)d_out;
  float* ws  = (float*)d_ws;
  const int E = in_sizes[2] / 2;

  // ---- workspace layout (float words) ----
  ushort_t* xb    = (ushort_t*)(ws + 0);            //  8192x512 bf16
  ushort_t* Wgp   = (ushort_t*)(ws + 2097152);      //  2x512x256
  ushort_t* W1ph  = (ushort_t*)(ws + 2228224);      //  768x512
  ushort_t* W1pl  = (ushort_t*)(ws + 2424832);
  ushort_t* W2ph  = (ushort_t*)(ws + 2621440);      //  512x256
  ushort_t* W2pl  = (ushort_t*)(ws + 2686976);
  ushort_t* Bpack = (ushort_t*)(ws + 2752512);      //  2x8192x256
  float*    s1    = ws + 4849664;                   //  2x8192
  float*    s2    = ws + 4866048;
  float*    pl    = ws + 4882432;                   //  8x8192
  ushort_t* pacc  = (ushort_t*)(ws + 4947968);      //  8x8192x256
  ushort_t* ehi   = (ushort_t*)(ws + 13336576);     //  8192x768
  ushort_t* elo   = (ushort_t*)(ws + 16482304);
  ushort_t* z1hi  = (ushort_t*)(ws + 19628032);     //  8192x512
  ushort_t* z1lo  = (ushort_t*)(ws + 21725184);
  float*    z2    = ws + 23822336;                  //  8192x256 f32

  // 1. fused prep: cast + weight packing + s-zero in ONE launch
  prep_all<<<4512, 256, 0, stream>>>(x, xb, Wg, Wgp, W1, W1ph, W1pl,
                                     W2, W2ph, W2pl, s1);
  // 2. fused h-GEMM -> Bpack + s1/s2 (XCD-aware block decode)
  gemm_h<<<dim3(4, 64, 2), 256, 0, stream>>>(xb, Wgp, a1, a2, Bpack, s1, s2);
  // 3. MFMA attention partials (R1 structure, verified local optimum)
  attn_mfma8<<<dim3(64, 4), 512, 0, stream>>>(Bpack, s1, s2, adj, pacc, pl);
  // 4. finalize -> embed emitted directly as hi/lo split (vectorized, G13)
  attn_finalize<<<8192, 128, 0, stream>>>(pacc, pl, bg, llm, ehi, elo);
  // 5. z1 = LR(embed @ W1 + b1) -> hi/lo (XCD-aware decode)
  gemm_mlp<<<dim3(8, 64), 256, 0, stream>>>(
      ehi, elo, W1ph, W1pl, b1, nullptr, z1hi, z1lo, 8192, 512, 768, MLP_SLOPE);
  // 6. z2 = LR(z1 @ W2 + b2) -> fp32 (XCD-aware decode)
  gemm_mlp<<<dim3(4, 64), 256, 0, stream>>>(
      z1hi, z1lo, W2ph, W2pl, b2, z2, nullptr, nullptr, 8192, 256, 512, MLP_SLOPE);
  // 7. edge dots
  pred_kernel<<<(E * 64 + 255) / 256, 256, 0, stream>>>(z2, ts, out, E);
}

// Round 12
// 556.425 us; speedup vs baseline: 1.1856x; 1.0026x over previous
//
#include <hip/hip_runtime.h>
#include <hip/hip_bf16.h>
#include <cstdint>
#include <cstddef>

#define ALPHA 0.2f
#define MLP_SLOPE 0.01f

typedef short bf16x8 __attribute__((ext_vector_type(8)));
typedef float f32x4 __attribute__((ext_vector_type(4)));
typedef unsigned short ushort_t;

// raw barrier: syncs LDS exchange WITHOUT draining vmcnt (global prefetches
// stay in flight across it).
#define ASM_BARRIER() __asm__ __volatile__("s_waitcnt lgkmcnt(0)\n\ts_barrier" ::: "memory")

__device__ __forceinline__ float lrelu(float x, float s) { return x > 0.f ? x : x * s; }
__device__ __forceinline__ ushort_t f2bf(float x) {
  __hip_bfloat16 h = __float2bfloat16(x);
  return *reinterpret_cast<ushort_t*>(&h);
}
__device__ __forceinline__ float bf2f(ushort_t u) {
  union { unsigned int i; float f; } v; v.i = ((unsigned int)u) << 16; return v.f;
}

// ---------------------------------------------------------------------------
// pack body: W[K,N] (batch offset b) into MFMA B-fragment order.
// ---------------------------------------------------------------------------
__device__ __forceinline__ void pack_body(
    const float* __restrict__ W, ushort_t* __restrict__ hi,
    ushort_t* __restrict__ lo, int K, int N, int gid, int batch)
{
  int lane = gid & 63;
  int kbc = K >> 5;
  int kblk = (gid >> 6) % kbc;
  int nblk = (gid >> 6) / kbc;
  size_t b = (size_t)batch * K * N;
  int col = nblk * 16 + (lane & 15);
  int krow = kblk * 32 + (lane >> 4) * 8;
  ushort_t h[8] __attribute__((aligned(16)));
  ushort_t l[8] __attribute__((aligned(16)));
#pragma unroll
  for (int e = 0; e < 8; ++e) {
    float v = W[b + (size_t)(krow + e) * N + col];
    h[e] = f2bf(v);
    l[e] = f2bf(v - bf2f(h[e]));
  }
  *(uint4*)&hi[b + (size_t)gid * 8] = *(uint4*)h;
  if (lo) *(uint4*)&lo[b + (size_t)gid * 8] = *(uint4*)l;
}

// ---------------------------------------------------------------------------
// prep_all: fuses tobf (4096 blocks) + pack Wg (128) + pack W1 (192) +
// pack W2 (64) + zero s1/s2 (32) into ONE launch = 4512 blocks. (R8 WIN)
// ---------------------------------------------------------------------------
__global__ __launch_bounds__(256) void prep_all(
    const float* __restrict__ x, ushort_t* __restrict__ xb,
    const float* __restrict__ Wg, ushort_t* __restrict__ Wgp,
    const float* __restrict__ W1, ushort_t* __restrict__ W1ph,
    ushort_t* __restrict__ W1pl,
    const float* __restrict__ W2, ushort_t* __restrict__ W2ph,
    ushort_t* __restrict__ W2pl, float* __restrict__ s12)
{
  const int b = blockIdx.x;
  const int t = threadIdx.x;
  if (b < 4096) {                       // tobf: x -> xb (bf16), 4 elems/thread
    int idx = b * 256 + t;
    float4 v = ((const float4*)x)[idx];
    ushort4 h;
    h.x = f2bf(v.x); h.y = f2bf(v.y); h.z = f2bf(v.z); h.w = f2bf(v.w);
    ((ushort4*)xb)[idx] = h;
  } else if (b < 4224) {                // pack Wg (2 heads x 64 blocks)
    int local = b - 4096;
    pack_body(Wg, Wgp, nullptr, 512, 256, (local & 63) * 256 + t, local >> 6);
  } else if (b < 4416) {                // pack W1 hi/lo
    int local = b - 4224;
    pack_body(W1, W1ph, W1pl, 768, 512, local * 256 + t, 0);
  } else if (b < 4480) {                // pack W2 hi/lo
    int local = b - 4416;
    pack_body(W2, W2ph, W2pl, 512, 256, local * 256 + t, 0);
  } else {                              // zero s1+s2 (contiguous 32768 floats)
    int idx = (b - 4480) * 256 + t;
    ((float4*)s12)[idx] = make_float4(0.f, 0.f, 0.f, 0.f);
  }
}

// ---------------------------------------------------------------------------
// Fused h-GEMM (R10 WIN: XCD-aware block decode).
// ---------------------------------------------------------------------------
__global__ __launch_bounds__(256, 2) void gemm_h(
    const ushort_t* __restrict__ xb, const ushort_t* __restrict__ Wgp,
    const float* __restrict__ a1, const float* __restrict__ a2,
    ushort_t* __restrict__ Bpack, float* __restrict__ s1,
    float* __restrict__ s2)
{
  __shared__ ushort_t Ab[2][128][40];
  const int t = threadIdx.x;
  // XCD-aware decode: lid in [0,512). xcd=lid&7 pins m%8; (n,head) fastest.
  const int lid = (blockIdx.z * gridDim.y + blockIdx.y) * gridDim.x + blockIdx.x;
  const int xcd = lid & 7;
  const int rest = lid >> 3;            // 0..63
  const int nh = rest & 7;              // n + 4*head
  const int head = nh >> 2;
  const int m0 = (xcd + 8 * (rest >> 3)) * 128;
  const int n0 = (nh & 3) * 64;
  const int wave = t >> 6;
  const int wm = (wave & 1) * 64, wn = (wave >> 1) * 32;
  const int l16 = t & 15, quad = (t >> 4) & 3, l63 = t & 63;
  const int sr = t >> 1, sp = (t & 1) * 16;
  const ushort_t* arow_g = xb + (size_t)(m0 + sr) * 512 + sp;
  const ushort_t* bp = Wgp + (size_t)head * 256 * 512;
  const int nb0 = (n0 + wn) >> 4;

  f32x4 acc[4][2];
#pragma unroll
  for (int i = 0; i < 4; ++i)
#pragma unroll
    for (int j = 0; j < 2; ++j) acc[i][j] = (f32x4){0.f, 0.f, 0.f, 0.f};

  uint4 r0, r1;
  r0 = *(const uint4*)(arow_g);
  r1 = *(const uint4*)(arow_g + 8);
  *(uint4*)&Ab[0][sr][sp] = r0;
  *(uint4*)&Ab[0][sr][sp + 8] = r1;
  __syncthreads();

  for (int kb = 0; kb < 16; ++kb) {
    const int cur = kb & 1, nxt = cur ^ 1;
    if (kb < 15) {
      const ushort_t* p = arow_g + (kb + 1) * 32;
      r0 = *(const uint4*)p;
      r1 = *(const uint4*)(p + 8);
    }
    bf16x8 Bf[2];
#pragma unroll
    for (int nt = 0; nt < 2; ++nt)
      Bf[nt] = *(const bf16x8*)&bp[(((size_t)(nb0 + nt) * 16 + kb) * 64 + l63) * 8];
    bf16x8 Af[4];
#pragma unroll
    for (int mt = 0; mt < 4; ++mt)
      Af[mt] = *(const bf16x8*)&Ab[cur][wm + mt * 16 + l16][quad * 8];
#pragma unroll
    for (int mt = 0; mt < 4; ++mt)
#pragma unroll
      for (int nt = 0; nt < 2; ++nt)
        acc[mt][nt] = __builtin_amdgcn_mfma_f32_16x16x32_bf16(
            Af[mt], Bf[nt], acc[mt][nt], 0, 0, 0);
    if (kb < 15) {
      *(uint4*)&Ab[nxt][sr][sp] = r0;
      *(uint4*)&Ab[nxt][sr][sp + 8] = r1;
    }
    __syncthreads();
  }

  // ---- epilogue 1: write Bpack in B-fragment order (bf16) ----
#pragma unroll
  for (int mt = 0; mt < 4; ++mt)
#pragma unroll
    for (int nt = 0; nt < 2; ++nt)
#pragma unroll
      for (int rg = 0; rg < 4; ++rg) {
        int j = m0 + wm + mt * 16 + quad * 4 + rg;
        int c = n0 + wn + nt * 16 + l16;
        int kblk = j >> 5;
        int laneb = ((j >> 3) & 3) * 16 + (c & 15);
        int e = j & 7;
        Bpack[(((size_t)head * 256 + kblk) * 16 + (c >> 4)) * 512 + laneb * 8 + e] =
            f2bf(acc[mt][nt][rg]);
      }
  // ---- epilogue 2: s1/s2 partial dots, shuffle-reduced over 16 cols ----
  float a1v[2], a2v[2];
#pragma unroll
  for (int nt = 0; nt < 2; ++nt) {
    int c = n0 + wn + nt * 16 + l16;
    a1v[nt] = a1[head * 256 + c];
    a2v[nt] = a2[head * 256 + c];
  }
#pragma unroll
  for (int mt = 0; mt < 4; ++mt)
#pragma unroll
    for (int rg = 0; rg < 4; ++rg) {
      float p1 = acc[mt][0][rg] * a1v[0] + acc[mt][1][rg] * a1v[1];
      float p2 = acc[mt][0][rg] * a2v[0] + acc[mt][1][rg] * a2v[1];
      p1 += __shfl_xor(p1, 1); p2 += __shfl_xor(p2, 1);
      p1 += __shfl_xor(p1, 2); p2 += __shfl_xor(p2, 2);
      p1 += __shfl_xor(p1, 4); p2 += __shfl_xor(p2, 4);
      p1 += __shfl_xor(p1, 8); p2 += __shfl_xor(p2, 8);
      if (l16 == 0) {
        int row = m0 + wm + mt * 16 + quad * 4 + rg;
        atomicAdd(&s1[head * 8192 + row], p1);
        atomicAdd(&s2[head * 8192 + row], p2);
      }
    }
}

// ---------------------------------------------------------------------------
// Pipelined split-bf16 MLP GEMM (R10 WIN: XCD-aware block decode).
// R11: Clo now null-guarded so z2 can be emitted as hi-only bf16.
// ---------------------------------------------------------------------------
__global__ __launch_bounds__(256, 2) void gemm_mlp(
    const ushort_t* __restrict__ Ahi, const ushort_t* __restrict__ Alo,
    const ushort_t* __restrict__ Bph, const ushort_t* __restrict__ Bpl,
    const float* __restrict__ bias, float* __restrict__ Cf,
    ushort_t* __restrict__ Chi, ushort_t* __restrict__ Clo,
    int M, int N, int K, float slope)
{
  __shared__ ushort_t Ah[2][128][40], Al[2][128][40];
  const int kbc = K >> 5;
  const int t = threadIdx.x;
  // XCD-aware decode: nwg = nx*64 (divisible by 8); xcd pins m%8.
  const int nx = gridDim.x;
  const int lid = blockIdx.y * nx + blockIdx.x;
  const int xcd = lid & 7;
  const int rest = lid >> 3;
  const int m0 = (xcd + 8 * (rest / nx)) * 128;
  const int n0 = (rest % nx) * 64;
  const int wave = t >> 6;
  const int wm = (wave & 1) * 64, wn = (wave >> 1) * 32;
  const int l16 = t & 15, quad = (t >> 4) & 3, l63 = t & 63;
  const int sr = t >> 1, sp = (t & 1) * 16;
  const ushort_t* ah_g = Ahi + (size_t)(m0 + sr) * K + sp;
  const ushort_t* al_g = Alo + (size_t)(m0 + sr) * K + sp;
  const int nb0 = (n0 + wn) >> 4;

  f32x4 acc[4][2];
#pragma unroll
  for (int i = 0; i < 4; ++i)
#pragma unroll
    for (int j = 0; j < 2; ++j) acc[i][j] = (f32x4){0.f, 0.f, 0.f, 0.f};

  uint4 rh0, rh1, rl0, rl1;
  rh0 = *(const uint4*)(ah_g);
  rh1 = *(const uint4*)(ah_g + 8);
  rl0 = *(const uint4*)(al_g);
  rl1 = *(const uint4*)(al_g + 8);
  *(uint4*)&Ah[0][sr][sp] = rh0;
  *(uint4*)&Ah[0][sr][sp + 8] = rh1;
  *(uint4*)&Al[0][sr][sp] = rl0;
  *(uint4*)&Al[0][sr][sp + 8] = rl1;
  __syncthreads();

  for (int kb = 0; kb < kbc; ++kb) {
    const int cur = kb & 1, nxt = cur ^ 1;
    if (kb + 1 < kbc) {
      const ushort_t* ph = ah_g + (kb + 1) * 32;
      const ushort_t* plo = al_g + (kb + 1) * 32;
      rh0 = *(const uint4*)ph;
      rh1 = *(const uint4*)(ph + 8);
      rl0 = *(const uint4*)plo;
      rl1 = *(const uint4*)(plo + 8);
    }
    bf16x8 bh[2], bl[2];
#pragma unroll
    for (int nt = 0; nt < 2; ++nt) {
      size_t o = (((size_t)(nb0 + nt) * kbc + kb) * 64 + l63) * 8;
      bh[nt] = *(const bf16x8*)&Bph[o];
      bl[nt] = *(const bf16x8*)&Bpl[o];
    }
    bf16x8 afh[4], afl[4];
#pragma unroll
    for (int mt = 0; mt < 4; ++mt) {
      afh[mt] = *(const bf16x8*)&Ah[cur][wm + mt * 16 + l16][quad * 8];
      afl[mt] = *(const bf16x8*)&Al[cur][wm + mt * 16 + l16][quad * 8];
    }
#pragma unroll
    for (int mt = 0; mt < 4; ++mt)
#pragma unroll
      for (int nt = 0; nt < 2; ++nt) {
        acc[mt][nt] = __builtin_amdgcn_mfma_f32_16x16x32_bf16(afh[mt], bh[nt], acc[mt][nt], 0, 0, 0);
        acc[mt][nt] = __builtin_amdgcn_mfma_f32_16x16x32_bf16(afh[mt], bl[nt], acc[mt][nt], 0, 0, 0);
        acc[mt][nt] = __builtin_amdgcn_mfma_f32_16x16x32_bf16(afl[mt], bh[nt], acc[mt][nt], 0, 0, 0);
      }
    if (kb + 1 < kbc) {
      *(uint4*)&Ah[nxt][sr][sp] = rh0;
      *(uint4*)&Ah[nxt][sr][sp + 8] = rh1;
      *(uint4*)&Al[nxt][sr][sp] = rl0;
      *(uint4*)&Al[nxt][sr][sp + 8] = rl1;
    }
    __syncthreads();
  }

#pragma unroll
  for (int mt = 0; mt < 4; ++mt)
#pragma unroll
    for (int nt = 0; nt < 2; ++nt)
#pragma unroll
      for (int rg = 0; rg < 4; ++rg) {
        int m = m0 + wm + mt * 16 + quad * 4 + rg;
        int n = n0 + wn + nt * 16 + l16;
        float v = lrelu(acc[mt][nt][rg] + bias[n], slope);
        size_t o = (size_t)m * N + n;
        if (Cf) Cf[o] = v;
        if (Chi) {
          ushort_t h = f2bf(v);
          Chi[o] = h;
          if (Clo) Clo[o] = f2bf(v - bf2f(h));
        }
      }
}

// ---------------------------------------------------------------------------
// MFMA attention v8 (R1, twice-verified): do not perturb (R3-R7 all failed).
// ---------------------------------------------------------------------------
__global__ __launch_bounds__(512, 1) void attn_mfma8(
    const ushort_t* __restrict__ Bpack, const float* __restrict__ s1g,
    const float* __restrict__ s2g, const int* __restrict__ adj,
    ushort_t* __restrict__ pacc, float* __restrict__ pl)
{
  __shared__ ushort_t Wlds[2][2][8][64][8];   // [buf][head][mt8][lane][8]
  const int t = threadIdx.x;
  const int i0 = blockIdx.x * 128;
  const int js = blockIdx.y;
  const int kbase = js * 2048;
  // generator mapping: row wr (0..127), k-octet kq (0..3)
  const int wr = t >> 2, kq = t & 3;
  const int glane = kq * 16 + (wr & 15);
  const int gmt = wr >> 4;                    // 0..7
  const float s1v0 = s1g[i0 + wr];
  const float s1v1 = s1g[8192 + i0 + wr];
  // consumer mapping: wave = (head, nh, rowgrp)
  const int wave = t >> 6;
  const int head = wave >> 2, nh = (wave >> 1) & 1, rg2 = wave & 1;
  const int l16 = t & 15, quad = (t >> 4) & 3;
  const int l63 = t & 63;
  f32x4 acc[4][8];
#pragma unroll
  for (int m = 0; m < 4; ++m)
#pragma unroll
    for (int n = 0; n < 8; ++n) acc[m][n] = (f32x4){0.f, 0.f, 0.f, 0.f};
  float rs0 = 0.f, rs1 = 0.f;

  const int* arow = adj + (size_t)(i0 + wr) * 8192;
  int4 pa0, pa1;
  float4 p20a, p20b, p21a, p21b;

  auto fetch = [&](int kk) {
    pa0 = *(const int4*)&arow[kk];
    pa1 = *(const int4*)&arow[kk + 4];
    p20a = *(const float4*)&s2g[kk];
    p20b = *(const float4*)&s2g[kk + 4];
    p21a = *(const float4*)&s2g[8192 + kk];
    p21b = *(const float4*)&s2g[8192 + kk + 4];
  };
  auto gen = [&](int buf) {
    int am[8] = {pa0.x, pa0.y, pa0.z, pa0.w, pa1.x, pa1.y, pa1.z, pa1.w};
    float s20[8] = {p20a.x, p20a.y, p20a.z, p20a.w, p20b.x, p20b.y, p20b.z, p20b.w};
    float s21[8] = {p21a.x, p21a.y, p21a.z, p21a.w, p21b.x, p21b.y, p21b.z, p21b.w};
    ushort_t w0[8] __attribute__((aligned(16)));
    ushort_t w1[8] __attribute__((aligned(16)));
#pragma unroll
    for (int e = 0; e < 8; ++e) {
      float e0 = s1v0 + s20[e];
      float e1 = s1v1 + s21[e];
      e0 = fmaxf(e0, 0.f) + ALPHA * fminf(e0, 0.f);
      e1 = fmaxf(e1, 0.f) + ALPHA * fminf(e1, 0.f);
      float v0 = am[e] > 0 ? __expf(e0) : 0.f;
      float v1 = am[e] > 0 ? __expf(e1) : 0.f;
      rs0 += v0; rs1 += v1;
      w0[e] = f2bf(v0); w1[e] = f2bf(v1);
    }
    *(uint4*)&Wlds[buf][0][gmt][glane][0] = *(uint4*)w0;
    *(uint4*)&Wlds[buf][1][gmt][glane][0] = *(uint4*)w1;
  };

  fetch(kbase + kq * 8);
  gen(0);
  fetch(kbase + 32 + kq * 8);
  ASM_BARRIER();

  for (int kt = 0; kt < 64; ++kt) {
    const int cur = kt & 1, nxt = cur ^ 1;
    const int kblk = js * 64 + kt;
    const ushort_t* bb =
        Bpack + ((((size_t)head * 256 + kblk) * 16 + nh * 8) * 64 + l63) * 8;
    bf16x8 Bf[8];
#pragma unroll
    for (int nt = 0; nt < 8; ++nt)
      Bf[nt] = *(const bf16x8*)&bb[nt * 512];
    bf16x8 Af[4];
#pragma unroll
    for (int mt = 0; mt < 4; ++mt)
      Af[mt] = *(const bf16x8*)&Wlds[cur][head][rg2 * 4 + mt][l63][0];
#pragma unroll
    for (int mt = 0; mt < 4; ++mt)
#pragma unroll
      for (int nt = 0; nt < 8; ++nt)
        acc[mt][nt] = __builtin_amdgcn_mfma_f32_16x16x32_bf16(
            Af[mt], Bf[nt], acc[mt][nt], 0, 0, 0);
    if (kt < 63) {
      gen(nxt);
      if (kt < 62) fetch(kbase + (kt + 2) * 32 + kq * 8);
    }
    ASM_BARRIER();
  }

  // denominators: reduce across the 4 kq lanes of each row
  rs0 += __shfl_xor(rs0, 1); rs0 += __shfl_xor(rs0, 2);
  rs1 += __shfl_xor(rs1, 1); rs1 += __shfl_xor(rs1, 2);
  if (kq == 0) {
    pl[((size_t)js * 2 + 0) * 8192 + i0 + wr] = rs0;
    pl[((size_t)js * 2 + 1) * 8192 + i0 + wr] = rs1;
  }
  // store bf16 partial numerators
  const int n0 = nh * 128;
#pragma unroll
  for (int mt = 0; mt < 4; ++mt)
#pragma unroll
    for (int nt = 0; nt < 8; ++nt)
#pragma unroll
      for (int rg = 0; rg < 4; ++rg) {
        int row = i0 + rg2 * 64 + mt * 16 + quad * 4 + rg;
        int col = n0 + nt * 16 + l16;
        pacc[(((size_t)js * 2 + head) * 8192 + row) * 256 + col] =
            f2bf(acc[mt][nt][rg]);
      }
}

// ---------------------------------------------------------------------------
// Finalize v2 (R9 WIN): vectorized per G13. 128 thr/block.
// ---------------------------------------------------------------------------
__global__ __launch_bounds__(128) void attn_finalize(
    const ushort_t* __restrict__ pacc, const float* __restrict__ pl,
    const float* __restrict__ bg, const float* __restrict__ llm,
    ushort_t* __restrict__ ehi, ushort_t* __restrict__ elo)
{
  __shared__ float red[2][2];
  const int r = blockIdx.x;
  const int t = threadIdx.x;            // 0..127
  const int wv = t >> 6, lane = t & 63;

  // llm passthrough: 4 cols/thread, vectorized
  {
    float4 v = *(const float4*)&llm[(size_t)r * 512 + t * 4];
    ushort4 h, l;
    h.x = f2bf(v.x); l.x = f2bf(v.x - bf2f(h.x));
    h.y = f2bf(v.y); l.y = f2bf(v.y - bf2f(h.y));
    h.z = f2bf(v.z); l.z = f2bf(v.z - bf2f(h.z));
    h.w = f2bf(v.w); l.w = f2bf(v.w - bf2f(h.w));
    *(ushort4*)&ehi[(size_t)r * 768 + t * 4] = h;
    *(ushort4*)&elo[(size_t)r * 768 + t * 4] = l;
  }
  // gnn part: 2 cols/thread
  const int c0 = t * 2;
  float o[2][2];
#pragma unroll
  for (int hh = 0; hh < 2; ++hh) {
    float n0 = 0.f, n1 = 0.f, l = 0.f;
#pragma unroll
    for (int js = 0; js < 4; ++js) {
      unsigned int u =
          *(const unsigned int*)&pacc[(((size_t)js * 2 + hh) * 8192 + r) * 256 + c0];
      n0 += bf2f((ushort_t)(u & 0xffffu));
      n1 += bf2f((ushort_t)(u >> 16));
      l += pl[((size_t)js * 2 + hh) * 8192 + r];
    }
    o[hh][0] = lrelu(n0 / l, ALPHA);
    o[hh][1] = lrelu(n1 / l, ALPHA);
  }
  float v0 = o[0][0] * o[0][0] + o[0][1] * o[0][1];
  float v1 = o[1][0] * o[1][0] + o[1][1] * o[1][1];
  for (int off = 32; off > 0; off >>= 1) {
    v0 += __shfl_xor(v0, off);
    v1 += __shfl_xor(v1, off);
  }
  if (lane == 0) { red[wv][0] = v0; red[wv][1] = v1; }
  __syncthreads();
  float nn0 = fmaxf(sqrtf(red[0][0] + red[1][0]), 1e-12f);
  float nn1 = fmaxf(sqrtf(red[0][1] + red[1][1]), 1e-12f);
  float2 bg0 = *(const float2*)&bg[c0];
  float2 bg1 = *(const float2*)&bg[256 + c0];
  float val0 = 0.5f * (o[0][0] / nn0 + bg0.x + o[1][0] / nn1 + bg1.x);
  float val1 = 0.5f * (o[0][1] / nn0 + bg0.y + o[1][1] / nn1 + bg1.y);
  ushort_t h0 = f2bf(val0), h1 = f2bf(val1);
  ushort2 hv; hv.x = h0; hv.y = h1;
  ushort2 lv; lv.x = f2bf(val0 - bf2f(h0)); lv.y = f2bf(val1 - bf2f(h1));
  *(ushort2*)&ehi[(size_t)r * 768 + 512 + c0] = hv;
  *(ushort2*)&elo[(size_t)r * 768 + 512 + c0] = lv;
}

// ---------------------------------------------------------------------------
// pred v2 (R11): z2 gathered as bf16 (4MB -> fits per-XCD L2; half the
// gather bytes of fp32). Each lane reads ushort4 (4 bf16) per row:
// 64 lanes x 4 = 256 cols. Numerics: z2 rounded to bf16 pre-dot (~2^-9 rel).
// ---------------------------------------------------------------------------
__global__ __launch_bounds__(256) void pred_kernel(
    const ushort_t* __restrict__ z2b, const int* __restrict__ ts,
    float* __restrict__ out, int E)
{
  const int gw = (blockIdx.x * 256 + threadIdx.x) >> 6;
  const int lane = threadIdx.x & 63;
  if (gw >= E) return;
  const int a = ts[gw * 2], b = ts[gw * 2 + 1];
  ushort4 va = ((const ushort4*)(z2b + (size_t)a * 256))[lane];
  ushort4 vb = ((const ushort4*)(z2b + (size_t)b * 256))[lane];
  float p = bf2f(va.x) * bf2f(vb.x) + bf2f(va.y) * bf2f(vb.y) +
            bf2f(va.z) * bf2f(vb.z) + bf2f(va.w) * bf2f(vb.w);
  for (int off = 32; off > 0; off >>= 1) p += __shfl_xor(p, off);
  if (lane == 0) out[gw] = p;
}

// ---------------------------------------------------------------------------
extern "C" void kernel_launch(void* const* d_in, const int* in_sizes, int n_in,
                              void* d_out, int out_size, void* d_ws, size_t ws_size,
                              hipStream_t stream) {
  const float* x   = (const float*)d_in[0];
  const int*   adj = (const int*)d_in[1];
  const int*   ts  = (const int*)d_in[2];
  const float* llm = (const float*)d_in[3];
  const float* Wg  = (const float*)d_in[4];
  const float* a1  = (const float*)d_in[5];
  const float* a2  = (const float*)d_in[6];
  const float* bg  = (const float*)d_in[7];
  const float* W1  = (const float*)d_in[8];
  const float* b1  = (const float*)d_in[9];
  const float* W2  = (const float*)d_in[10];
  const float* b2  = (const float*)d_in[11];
  float* out = (float*)d_out;
  float* ws  = (float*)d_ws;
  const int E = in_sizes[2] / 2;

  // ---- workspace layout (float words) ----
  ushort_t* xb    = (ushort_t*)(ws + 0);            //  8192x512 bf16
  ushort_t* Wgp   = (ushort_t*)(ws + 2097152);      //  2x512x256
  ushort_t* W1ph  = (ushort_t*)(ws + 2228224);      //  768x512
  ushort_t* W1pl  = (ushort_t*)(ws + 2424832);
  ushort_t* W2ph  = (ushort_t*)(ws + 2621440);      //  512x256
  ushort_t* W2pl  = (ushort_t*)(ws + 2686976);
  ushort_t* Bpack = (ushort_t*)(ws + 2752512);      //  2x8192x256
  float*    s1    = ws + 4849664;                   //  2x8192
  float*    s2    = ws + 4866048;
  float*    pl    = ws + 4882432;                   //  8x8192
  ushort_t* pacc  = (ushort_t*)(ws + 4947968);      //  8x8192x256
  ushort_t* ehi   = (ushort_t*)(ws + 13336576);     //  8192x768
  ushort_t* elo   = (ushort_t*)(ws + 16482304);
  ushort_t* z1hi  = (ushort_t*)(ws + 19628032);     //  8192x512
  ushort_t* z1lo  = (ushort_t*)(ws + 21725184);
  ushort_t* z2b   = (ushort_t*)(ws + 23822336);     //  8192x256 bf16

  // 1. fused prep: cast + weight packing + s-zero in ONE launch
  prep_all<<<4512, 256, 0, stream>>>(x, xb, Wg, Wgp, W1, W1ph, W1pl,
                                     W2, W2ph, W2pl, s1);
  // 2. fused h-GEMM -> Bpack + s1/s2 (XCD-aware block decode)
  gemm_h<<<dim3(4, 64, 2), 256, 0, stream>>>(xb, Wgp, a1, a2, Bpack, s1, s2);
  // 3. MFMA attention partials (R1 structure, verified local optimum)
  attn_mfma8<<<dim3(64, 4), 512, 0, stream>>>(Bpack, s1, s2, adj, pacc, pl);
  // 4. finalize -> embed emitted directly as hi/lo split (vectorized, G13)
  attn_finalize<<<8192, 128, 0, stream>>>(pacc, pl, bg, llm, ehi, elo);
  // 5. z1 = LR(embed @ W1 + b1) -> hi/lo (XCD-aware decode)
  gemm_mlp<<<dim3(8, 64), 256, 0, stream>>>(
      ehi, elo, W1ph, W1pl, b1, nullptr, z1hi, z1lo, 8192, 512, 768, MLP_SLOPE);
  // 6. z2 = LR(z1 @ W2 + b2) -> bf16 (hi-only, for L2-resident pred gather)
  gemm_mlp<<<dim3(4, 64), 256, 0, stream>>>(
      z1hi, z1lo, W2ph, W2pl, b2, nullptr, z2b, nullptr, 8192, 256, 512, MLP_SLOPE);
  // 7. edge dots (bf16 gather, half traffic, per-XCD L2-resident)
  pred_kernel<<<(E * 64 + 255) / 256, 256, 0, stream>>>(z2b, ts, out, E);
}